// Round 1
// 1829.718 us; speedup vs baseline: 1.1141x; 1.1141x over previous
//
#include <hip/hip_runtime.h>

#define S_DIM 1024
#define N_DIM 384
#define CZ    128
#define CM    64
#define H_DIM 8
#define CH    32
#define COPM  32
#define HID   256
#define SD    32768   // S_DIM*CH
#define MO    12288   // N_DIM*COPM
#define LDSW  72      // padded LDS row stride (ushorts), 144B = 16B-aligned

typedef __attribute__((ext_vector_type(8))) short  short8;
typedef __attribute__((ext_vector_type(4))) float  floatx4;

__device__ __forceinline__ float bf2f(unsigned short u){
  union { unsigned int u; float f; } v; v.u = ((unsigned int)u)<<16; return v.f;
}
__device__ __forceinline__ unsigned short f2bf(float f){
  union { float f; unsigned int u; } v; v.f = f;
  return (unsigned short)((v.u + 0x7fffu + ((v.u>>16)&1u)) >> 16);
}
__device__ __forceinline__ float red64(float x){
  #pragma unroll
  for (int off=1; off<64; off<<=1) x += __shfl_xor(x, off, 64);
  return x;
}
__device__ __forceinline__ float red16(float x){
  #pragma unroll
  for (int off=1; off<16; off<<=1) x += __shfl_xor(x, off, 64);
  return x;
}
__device__ __forceinline__ void gload16(const void* g, void* l){
  __builtin_amdgcn_global_load_lds((__attribute__((address_space(1))) void*)(g),
                                   (__attribute__((address_space(3))) void*)(l), 16, 0, 0);
}

// ---------------- generic fp32 -> bf16 convert ----------------
__global__ void kcvt(const float* __restrict__ w, unsigned short* __restrict__ o, int n){
  int i = blockIdx.x*256 + threadIdx.x;
  if (i < n) o[i] = f2bf(w[i]);
}

// ---------------- K1: logits[h][i][j] = LN(z)@wz^T + mask ----------------
__global__ __launch_bounds__(256) void k1_logits(
    const float* __restrict__ z, const float* __restrict__ tm,
    const float* __restrict__ g, const float* __restrict__ b,
    const float* __restrict__ wz, float* __restrict__ logits)
{
  int idx  = blockIdx.x*4 + (threadIdx.x>>6);      // (i,j) flat, 147456
  int lane = threadIdx.x & 63;
  const float* zp = z + (size_t)idx*CZ;
  float x0 = zp[lane], x1 = zp[lane+64];
  float mu = red64(x0+x1) * (1.0f/128.0f);
  float d0 = x0-mu, d1 = x1-mu;
  float var = red64(d0*d0 + d1*d1) * (1.0f/128.0f);
  float rs = rsqrtf(var + 1e-5f);
  float y0 = d0*rs*g[lane]    + b[lane];
  float y1 = d1*rs*g[lane+64] + b[lane+64];
  float mterm = (1.0f - tm[idx]) * (-1e6f);
  #pragma unroll
  for (int h=0; h<H_DIM; ++h){
    float p = y0*wz[h*CZ+lane] + y1*wz[h*CZ+64+lane];
    p = red64(p);
    if (lane==0) logits[(size_t)h*N_DIM*N_DIM + idx] = p + mterm;
  }
}

// ---------------- K2: softmax rows -> w_att bf16 ----------------
__global__ __launch_bounds__(256) void k2_softmax(
    const float* __restrict__ logits, unsigned short* __restrict__ watt)
{
  int row  = blockIdx.x*4 + (threadIdx.x>>6);      // 3072 rows (h*384+i)
  int lane = threadIdx.x & 63;
  const float* p = logits + (size_t)row*N_DIM;
  float v[6]; float mx = -3.4e38f;
  #pragma unroll
  for (int e=0;e<6;++e){ v[e] = p[lane + e*64]; mx = fmaxf(mx, v[e]); }
  #pragma unroll
  for (int off=1; off<64; off<<=1) mx = fmaxf(mx, __shfl_xor(mx, off, 64));
  float sum = 0.f;
  #pragma unroll
  for (int e=0;e<6;++e){ v[e] = __expf(v[e]-mx); sum += v[e]; }
  sum = red64(sum);
  float inv = 1.0f/sum;
  #pragma unroll
  for (int e=0;e<6;++e) watt[(size_t)row*N_DIM + lane + e*64] = f2bf(v[e]*inv);
}

// ---------------- K3: mn = LN(m) (bf16), v2[h][(s,d)][j] = mn@wm^T ----------------
__global__ __launch_bounds__(256) void k3_lnm_v(
    const float* __restrict__ m, const float* __restrict__ g, const float* __restrict__ b,
    const float* __restrict__ wm, unsigned short* __restrict__ mn, unsigned short* __restrict__ v2)
{
  __shared__ float mnL[16*64];
  int s = blockIdx.y, j0 = blockIdx.x*16, t = threadIdx.x;
  {
    int r = t>>4, q = t&15;
    size_t row = (size_t)s*N_DIM + j0 + r;
    float4 x = *(const float4*)(m + row*CM + q*4);
    float mu = red16(x.x+x.y+x.z+x.w) * (1.0f/64.0f);
    float4 d = {x.x-mu, x.y-mu, x.z-mu, x.w-mu};
    float var = red16(d.x*d.x+d.y*d.y+d.z*d.z+d.w*d.w) * (1.0f/64.0f);
    float rs = rsqrtf(var + 1e-5f);
    float4 y;
    y.x = d.x*rs*g[q*4+0] + b[q*4+0];
    y.y = d.y*rs*g[q*4+1] + b[q*4+1];
    y.z = d.z*rs*g[q*4+2] + b[q*4+2];
    y.w = d.w*rs*g[q*4+3] + b[q*4+3];
    mnL[r*64+q*4+0]=y.x; mnL[r*64+q*4+1]=y.y; mnL[r*64+q*4+2]=y.z; mnL[r*64+q*4+3]=y.w;
    ushort4 u4 = {f2bf(y.x), f2bf(y.y), f2bf(y.z), f2bf(y.w)};
    *(ushort4*)(mn + row*CM + q*4) = u4;
  }
  __syncthreads();
  float acc[16];
  #pragma unroll
  for (int r=0;r<16;++r) acc[r]=0.f;
  const float4* wm4  = (const float4*)wm;
  const float4* mnL4 = (const float4*)mnL;
  #pragma unroll 4
  for (int c4=0;c4<16;++c4){
    float4 w = wm4[t*16 + c4];
    #pragma unroll
    for (int r=0;r<16;++r){
      float4 x = mnL4[r*16 + c4];
      acc[r] += x.x*w.x + x.y*w.y + x.z*w.z + x.w*w.w;
    }
  }
  int h = t>>5, d2 = t&31;
  short8 p0, p1;
  #pragma unroll
  for (int e=0;e<8;++e){ p0[e] = (short)f2bf(acc[e]); p1[e] = (short)f2bf(acc[8+e]); }
  unsigned short* dst = v2 + ((size_t)h*SD + (size_t)s*CH + d2)*N_DIM + j0;
  *(short8*)dst       = p0;
  *(short8*)(dst + 8) = p1;
}

// ---------------- K7: num[i][j] = max(1, sum_s mask[s,i]*mask[s,j]) ----------------
__global__ __launch_bounds__(256) void k7_num(
    const float* __restrict__ mask, float* __restrict__ num)
{
  __shared__ float mA[64*16], mB[64*16];
  int i0 = blockIdx.y*16, j0 = blockIdx.x*16, t = threadIdx.x;
  int ti = t>>4, tj = t&15;
  float acc = 0.f;
  for (int s0=0; s0<S_DIM; s0+=64){
    #pragma unroll
    for (int k=0;k<4;++k){
      int idx = t + k*256; int ss = idx>>4, c = idx&15;
      mA[idx] = mask[(size_t)(s0+ss)*N_DIM + i0 + c];
      mB[idx] = mask[(size_t)(s0+ss)*N_DIM + j0 + c];
    }
    __syncthreads();
    #pragma unroll 8
    for (int ss=0; ss<64; ++ss) acc += mA[ss*16+ti] * mB[ss*16+tj];
    __syncthreads();
  }
  num[(size_t)(i0+ti)*N_DIM + j0+tj] = fmaxf(acc, 1.0f);
}

// ---------------- shared 128x128 A*B^T core (m97 pattern, XOR-swizzled LDS) ----------------
// T2 swizzle adapted for global_load_lds (rule #21): LDS dest stays LINEAR
// (gload_lds writes base+lane*16), the 16B slot within each row is
// pre-swizzled on the GLOBAL source address, and the ds_read applies the
// same XOR. slot' = slot ^ (row&7) spreads one wave's 64-lane ds_read_b128
// across all 32 banks (was: slot fixed per quad -> 16 lanes on one 4-bank
// group = ~16-way conflict = 1.27e8 SQ_LDS_BANK_CONFLICT in k8).
__device__ __forceinline__ void gemm_bt_core(
    const unsigned short* __restrict__ A, const unsigned short* __restrict__ B,
    int lda, int ldb, int K,
    unsigned short* As, unsigned short* Bs, floatx4 acc[4][4],
    int wr, int wc, int ln15, int quad)
{
  int t = threadIdx.x;
  for (int k0=0; k0<K; k0+=64){
    #pragma unroll
    for (int it=0; it<4; ++it){
      int ch = it*256 + t;                  // 1024 chunks of 16B per operand
      int row = ch>>3, slot = ch&7;
      int koff = (slot ^ (row&7))*8;        // inverse-swizzled global source
      gload16(A + (size_t)row*lda + k0 + koff, As + ch*8);
      gload16(B + (size_t)row*ldb + k0 + koff, Bs + ch*8);
    }
    __syncthreads();
    #pragma unroll
    for (int kk=0; kk<2; ++kk){
      // row&7 == ln15&7 for all fragment rows (wr, x*16 are multiples of 8)
      int sw = (((kk<<2) | quad) ^ (ln15 & 7)) << 3;   // swizzled 16B slot (ushorts)
      short8 af[4], bfr[4];
      #pragma unroll
      for (int x=0;x<4;++x) af[x]  = *(const short8*)(As + ((wr + x*16 + ln15)<<6) + sw);
      #pragma unroll
      for (int x=0;x<4;++x) bfr[x] = *(const short8*)(Bs + ((wc + x*16 + ln15)<<6) + sw);
      #pragma unroll
      for (int ti=0;ti<4;++ti)
        #pragma unroll
        for (int tj=0;tj<4;++tj)
          acc[ti][tj] = __builtin_amdgcn_mfma_f32_16x16x32_bf16(af[ti], bfr[tj], acc[ti][tj], 0, 0, 0);
    }
    __syncthreads();
  }
}

// ---------------- K4: per-head attention o2[h][i][(s,d)] = att @ v2^T ----------------
__global__ __launch_bounds__(256) void k4_attn(
    const unsigned short* __restrict__ watt, const unsigned short* __restrict__ v2,
    unsigned short* __restrict__ o2)
{
  __shared__ unsigned short smem[16384];
  int t = threadIdx.x, lane = t&63, w = t>>6;
  int ln15 = lane&15, quad = lane>>4;
  int wr = (w>>1)*64, wc = (w&1)*64;
  int nb = blockIdx.x, mb = blockIdx.y, h = blockIdx.z;
  const unsigned short* A = watt + (size_t)h*N_DIM*N_DIM + (size_t)(mb*128)*N_DIM;
  const unsigned short* B = v2 + ((size_t)h*SD + (size_t)nb*128)*N_DIM;
  floatx4 acc[4][4];
  #pragma unroll
  for (int ti=0;ti<4;++ti)
    #pragma unroll
    for (int tj=0;tj<4;++tj) acc[ti][tj] = (floatx4){0.f,0.f,0.f,0.f};
  gemm_bt_core(A, B, N_DIM, N_DIM, N_DIM, smem, smem+8192, acc, wr, wc, ln15, quad);
  unsigned short* C = o2 + ((size_t)h*N_DIM + mb*128)*SD + nb*128;
  #pragma unroll
  for (int ti=0;ti<4;++ti)
    #pragma unroll
    for (int tj=0;tj<4;++tj)
      #pragma unroll
      for (int r=0;r<4;++r)
        C[(size_t)(wr+ti*16+quad*4+r)*SD + wc + tj*16 + ln15] = f2bf(acc[ti][tj][r]);
}

// ---------------- K5m: MFMA PWA update: m1 = m + (sigmoid(mn@wg^T) * o) @ wo^T ----------------
__global__ __launch_bounds__(256) void k5m(
    const float* __restrict__ m_in, const unsigned short* __restrict__ mn,
    const unsigned short* __restrict__ o2,
    const unsigned short* __restrict__ wgb, const unsigned short* __restrict__ wob,
    float* __restrict__ m1_out)
{
  __shared__ unsigned short tA[128*LDSW];
  __shared__ unsigned short uC[128*LDSW];
  int i = blockIdx.y, s0 = blockIdx.x*128, t = threadIdx.x;
  int lane = t&63, w = t>>6, ln15 = lane&15, quad = lane>>4;
  int wr = (w>>1)*64, wc2 = (w&1)*32;

  { // stage mn rows (s0+r, i) -> tA
    int r = t>>1, hf = t&1;
    const unsigned short* src = mn + (((size_t)(s0+r))*N_DIM + i)*CM + hf*32;
    #pragma unroll
    for (int e=0;e<4;++e)
      *(short8*)(tA + r*LDSW + hf*32 + e*8) = *(const short8*)(src + e*8);
  }
  __syncthreads();

  short8 af[4][2];
  #pragma unroll
  for (int x=0;x<4;++x)
    #pragma unroll
    for (int kk=0;kk<2;++kk)
      af[x][kk] = *(const short8*)(tA + (wr + x*16 + ln15)*LDSW + kk*32 + quad*8);

  floatx4 mAcc[4][2];
  #pragma unroll
  for (int x=0;x<4;++x){ mAcc[x][0]=(floatx4){0,0,0,0}; mAcc[x][1]=(floatx4){0,0,0,0}; }

  for (int hc=0; hc<4; ++hc){
    floatx4 gA[4][2];
    #pragma unroll
    for (int x=0;x<4;++x){ gA[x][0]=(floatx4){0,0,0,0}; gA[x][1]=(floatx4){0,0,0,0}; }
    short8 bg[2][2];
    #pragma unroll
    for (int xj=0;xj<2;++xj)
      #pragma unroll
      for (int kk=0;kk<2;++kk)
        bg[xj][kk] = *(const short8*)(wgb + (hc*64 + wc2 + xj*16 + ln15)*CM + kk*32 + quad*8);
    #pragma unroll
    for (int kk=0;kk<2;++kk)
      #pragma unroll
      for (int x=0;x<4;++x)
        #pragma unroll
        for (int xj=0;xj<2;++xj)
          gA[x][xj] = __builtin_amdgcn_mfma_f32_16x16x32_bf16(af[x][kk], bg[xj][kk], gA[x][xj], 0,0,0);
    __syncthreads();  // prev chunk's uC reads complete
    #pragma unroll
    for (int x=0;x<4;++x)
      #pragma unroll
      for (int xj=0;xj<2;++xj)
        #pragma unroll
        for (int r=0;r<4;++r){
          int s = wr + x*16 + quad*4 + r, c = wc2 + xj*16 + ln15;
          int hd = hc*64 + c, h = hd>>5, d = hd&31;
          float gv = 1.f/(1.f+__expf(-gA[x][xj][r]));
          float ov = bf2f(o2[((size_t)(h*N_DIM + i))*SD + (size_t)(s0+s)*CH + d]);
          uC[s*LDSW + c] = f2bf(gv*ov);
        }
    __syncthreads();
    short8 au[4][2], bo[2][2];
    #pragma unroll
    for (int x=0;x<4;++x)
      #pragma unroll
      for (int kk=0;kk<2;++kk)
        au[x][kk] = *(const short8*)(uC + (wr + x*16 + ln15)*LDSW + kk*32 + quad*8);
    #pragma unroll
    for (int xj=0;xj<2;++xj)
      #pragma unroll
      for (int kk=0;kk<2;++kk)
        bo[xj][kk] = *(const short8*)(wob + (wc2 + xj*16 + ln15)*HID + hc*64 + kk*32 + quad*8);
    #pragma unroll
    for (int kk=0;kk<2;++kk)
      #pragma unroll
      for (int x=0;x<4;++x)
        #pragma unroll
        for (int xj=0;xj<2;++xj)
          mAcc[x][xj] = __builtin_amdgcn_mfma_f32_16x16x32_bf16(au[x][kk], bo[xj][kk], mAcc[x][xj], 0,0,0);
  }
  #pragma unroll
  for (int x=0;x<4;++x)
    #pragma unroll
    for (int xj=0;xj<2;++xj)
      #pragma unroll
      for (int r=0;r<4;++r){
        int s = wr + x*16 + quad*4 + r, c = wc2 + xj*16 + ln15;
        size_t gi = (((size_t)(s0+s))*N_DIM + i)*CM + c;
        m1_out[gi] = m_in[gi] + mAcc[x][xj][r];
      }
}

// ---------------- K6m: MFMA SwiGLU transition + LN + a/b projections ----------------
__global__ __launch_bounds__(256) void k6m(
    float* __restrict__ m_io, const float* __restrict__ mask,
    const float* __restrict__ lntg, const float* __restrict__ lntb,
    const unsigned short* __restrict__ fc1b, const unsigned short* __restrict__ fc2b,
    const unsigned short* __restrict__ fc3b,
    const float* __restrict__ lnog, const float* __restrict__ lnob,
    const unsigned short* __restrict__ wabb,
    unsigned short* __restrict__ a2g, unsigned short* __restrict__ b2g)
{
  __shared__ unsigned short tA[128*LDSW];
  __shared__ unsigned short uC[128*LDSW];
  __shared__ float maskL[128];
  int i = blockIdx.y, s0 = blockIdx.x*128, t = threadIdx.x;
  int lane = t&63, w = t>>6, ln15 = lane&15, quad = lane>>4;
  int wr = (w>>1)*64, wc2 = (w&1)*32;

  { // LN1 of m1 rows -> tA (bf16)
    int r = t>>1, hf = t&1;
    const float4* src = (const float4*)(m_io + (((size_t)(s0+r))*N_DIM + i)*CM + hf*32);
    float xv[32];
    #pragma unroll
    for (int e=0;e<8;++e){
      float4 x = src[e];
      xv[e*4+0]=x.x; xv[e*4+1]=x.y; xv[e*4+2]=x.z; xv[e*4+3]=x.w;
    }
    float sm = 0.f;
    #pragma unroll
    for (int e=0;e<32;++e) sm += xv[e];
    sm += __shfl_xor(sm, 1, 64);
    float mu = sm * (1.0f/64.0f);
    float vr = 0.f;
    #pragma unroll
    for (int e=0;e<32;++e){ float d = xv[e]-mu; vr += d*d; }
    vr += __shfl_xor(vr, 1, 64);
    float rs = rsqrtf(vr*(1.0f/64.0f) + 1e-5f);
    #pragma unroll
    for (int e=0;e<8;++e){
      ushort4 pk;
      pk.x = f2bf((xv[e*4+0]-mu)*rs*lntg[hf*32+e*4+0] + lntb[hf*32+e*4+0]);
      pk.y = f2bf((xv[e*4+1]-mu)*rs*lntg[hf*32+e*4+1] + lntb[hf*32+e*4+1]);
      pk.z = f2bf((xv[e*4+2]-mu)*rs*lntg[hf*32+e*4+2] + lntb[hf*32+e*4+2]);
      pk.w = f2bf((xv[e*4+3]-mu)*rs*lntg[hf*32+e*4+3] + lntb[hf*32+e*4+3]);
      *(ushort4*)(tA + r*LDSW + hf*32 + e*4) = pk;
    }
    if (t < 128) maskL[t] = mask[(size_t)(s0+t)*N_DIM + i];
  }
  __syncthreads();

  short8 af[4][2];
  #pragma unroll
  for (int x=0;x<4;++x)
    #pragma unroll
    for (int kk=0;kk<2;++kk)
      af[x][kk] = *(const short8*)(tA + (wr + x*16 + ln15)*LDSW + kk*32 + quad*8);

  floatx4 mAcc[4][2];
  #pragma unroll
  for (int x=0;x<4;++x){ mAcc[x][0]=(floatx4){0,0,0,0}; mAcc[x][1]=(floatx4){0,0,0,0}; }

  for (int hc=0; hc<4; ++hc){
    floatx4 h1A[4][2], h2A[4][2];
    #pragma unroll
    for (int x=0;x<4;++x){
      h1A[x][0]=(floatx4){0,0,0,0}; h1A[x][1]=(floatx4){0,0,0,0};
      h2A[x][0]=(floatx4){0,0,0,0}; h2A[x][1]=(floatx4){0,0,0,0};
    }
    short8 b1[2][2], b2[2][2];
    #pragma unroll
    for (int xj=0;xj<2;++xj)
      #pragma unroll
      for (int kk=0;kk<2;++kk){
        int hrow = hc*64 + wc2 + xj*16 + ln15;
        b1[xj][kk] = *(const short8*)(fc1b + hrow*CM + kk*32 + quad*8);
        b2[xj][kk] = *(const short8*)(fc2b + hrow*CM + kk*32 + quad*8);
      }
    #pragma unroll
    for (int kk=0;kk<2;++kk)
      #pragma unroll
      for (int x=0;x<4;++x)
        #pragma unroll
        for (int xj=0;xj<2;++xj){
          h1A[x][xj] = __builtin_amdgcn_mfma_f32_16x16x32_bf16(af[x][kk], b1[xj][kk], h1A[x][xj], 0,0,0);
          h2A[x][xj] = __builtin_amdgcn_mfma_f32_16x16x32_bf16(af[x][kk], b2[xj][kk], h2A[x][xj], 0,0,0);
        }
    __syncthreads();  // prev chunk's uC reads complete
    #pragma unroll
    for (int x=0;x<4;++x)
      #pragma unroll
      for (int xj=0;xj<2;++xj)
        #pragma unroll
        for (int r=0;r<4;++r){
          int s = wr + x*16 + quad*4 + r, c = wc2 + xj*16 + ln15;
          float hv = h1A[x][xj][r];
          float u = hv/(1.f+__expf(-hv)) * h2A[x][xj][r];
          uC[s*LDSW + c] = f2bf(u);
        }
    __syncthreads();
    short8 au[4][2], b3[2][2];
    #pragma unroll
    for (int x=0;x<4;++x)
      #pragma unroll
      for (int kk=0;kk<2;++kk)
        au[x][kk] = *(const short8*)(uC + (wr + x*16 + ln15)*LDSW + kk*32 + quad*8);
    #pragma unroll
    for (int xj=0;xj<2;++xj)
      #pragma unroll
      for (int kk=0;kk<2;++kk)
        b3[xj][kk] = *(const short8*)(fc3b + (wc2 + xj*16 + ln15)*HID + hc*64 + kk*32 + quad*8);
    #pragma unroll
    for (int kk=0;kk<2;++kk)
      #pragma unroll
      for (int x=0;x<4;++x)
        #pragma unroll
        for (int xj=0;xj<2;++xj)
          mAcc[x][xj] = __builtin_amdgcn_mfma_f32_16x16x32_bf16(au[x][kk], b3[xj][kk], mAcc[x][xj], 0,0,0);
  }
  __syncthreads();  // all uC/tA reads complete

  // m2 = m1 + mAcc -> global (fp32) + tA (bf16)
  #pragma unroll
  for (int x=0;x<4;++x)
    #pragma unroll
    for (int xj=0;xj<2;++xj)
      #pragma unroll
      for (int r=0;r<4;++r){
        int s = wr + x*16 + quad*4 + r, c = wc2 + xj*16 + ln15;
        size_t gi = (((size_t)(s0+s))*N_DIM + i)*CM + c;
        float m2v = m_io[gi] + mAcc[x][xj][r];
        m_io[gi] = m2v;
        tA[s*LDSW + c] = f2bf(m2v);
      }
  __syncthreads();

  { // LN2 from tA -> mo in uC
    int r = t>>1, hf = t&1;
    float xv[32];
    #pragma unroll
    for (int e=0;e<32;++e) xv[e] = bf2f(tA[r*LDSW + hf*32 + e]);
    float sm = 0.f;
    #pragma unroll
    for (int e=0;e<32;++e) sm += xv[e];
    sm += __shfl_xor(sm, 1, 64);
    float mu = sm * (1.0f/64.0f);
    float vr = 0.f;
    #pragma unroll
    for (int e=0;e<32;++e){ float d = xv[e]-mu; vr += d*d; }
    vr += __shfl_xor(vr, 1, 64);
    float rs = rsqrtf(vr*(1.0f/64.0f) + 1e-5f);
    #pragma unroll
    for (int e=0;e<8;++e){
      ushort4 pk;
      pk.x = f2bf((xv[e*4+0]-mu)*rs*lnog[hf*32+e*4+0] + lnob[hf*32+e*4+0]);
      pk.y = f2bf((xv[e*4+1]-mu)*rs*lnog[hf*32+e*4+1] + lnob[hf*32+e*4+1]);
      pk.z = f2bf((xv[e*4+2]-mu)*rs*lnog[hf*32+e*4+2] + lnob[hf*32+e*4+2]);
      pk.w = f2bf((xv[e*4+3]-mu)*rs*lnog[hf*32+e*4+3] + lnob[hf*32+e*4+3]);
      *(ushort4*)(uC + r*LDSW + hf*32 + e*4) = pk;
    }
  }
  __syncthreads();

  // GEMM3: mo @ [wa;wb]^T (K=64), masked transposed store
  floatx4 ab[4][2];
  #pragma unroll
  for (int x=0;x<4;++x){ ab[x][0]=(floatx4){0,0,0,0}; ab[x][1]=(floatx4){0,0,0,0}; }
  short8 am[4][2], bw[2][2];
  #pragma unroll
  for (int x=0;x<4;++x)
    #pragma unroll
    for (int kk=0;kk<2;++kk)
      am[x][kk] = *(const short8*)(uC + (wr + x*16 + ln15)*LDSW + kk*32 + quad*8);
  #pragma unroll
  for (int xj=0;xj<2;++xj)
    #pragma unroll
    for (int kk=0;kk<2;++kk)
      bw[xj][kk] = *(const short8*)(wabb + (wc2 + xj*16 + ln15)*CM + kk*32 + quad*8);
  #pragma unroll
  for (int kk=0;kk<2;++kk)
    #pragma unroll
    for (int x=0;x<4;++x)
      #pragma unroll
      for (int xj=0;xj<2;++xj)
        ab[x][xj] = __builtin_amdgcn_mfma_f32_16x16x32_bf16(am[x][kk], bw[xj][kk], ab[x][xj], 0,0,0);
  #pragma unroll
  for (int x=0;x<4;++x)
    #pragma unroll
    for (int xj=0;xj<2;++xj){
      int c = wc2 + xj*16 + ln15;
      int sbase = wr + x*16 + quad*4;
      ushort4 pk;
      #pragma unroll
      for (int r=0;r<4;++r) pk[r] = f2bf(ab[x][xj][r] * maskL[sbase+r]);
      unsigned short* dst = (c < 32)
        ? (a2g + ((size_t)i*COPM + c)*S_DIM + s0 + sbase)
        : (b2g + ((size_t)i*COPM + (c-32))*S_DIM + s0 + sbase);
      *(ushort4*)dst = pk;
    }
}

// ---------------- K8: outer-product GEMM + fused w_out epilogue -> z ----------------
__global__ __launch_bounds__(256) void k8_outer(
    const unsigned short* __restrict__ a2, const unsigned short* __restrict__ b2,
    const unsigned short* __restrict__ woutb, const float* __restrict__ num,
    const float* __restrict__ zin, const float* __restrict__ bout,
    float* __restrict__ zout)
{
  __shared__ unsigned short smem[16384];
  int t = threadIdx.x, lane = t&63, w = t>>6;
  int ln15 = lane&15, quad = lane>>4;
  int wr = (w>>1)*64, wc = (w&1)*64;
  int nb = blockIdx.x, mb = blockIdx.y;
  const unsigned short* A = a2 + (size_t)(mb*128)*S_DIM;
  const unsigned short* B = b2 + (size_t)(nb*128)*S_DIM;
  floatx4 acc[4][4];
  #pragma unroll
  for (int ti=0;ti<4;++ti)
    #pragma unroll
    for (int tj=0;tj<4;++tj) acc[ti][tj] = (floatx4){0.f,0.f,0.f,0.f};
  gemm_bt_core(A, B, S_DIM, S_DIM, S_DIM, smem, smem+8192, acc, wr, wc, ln15, quad);
  unsigned short* P = smem;
  #pragma unroll
  for (int ti=0;ti<4;++ti)
    #pragma unroll
    for (int tj=0;tj<4;++tj)
      #pragma unroll
      for (int r=0;r<4;++r)
        P[(wr+ti*16+quad*4+r)*128 + wc+tj*16+ln15] = f2bf(acc[ti][tj][r]);
  __syncthreads();
  int i0 = mb*4, j0 = nb*4;
  #pragma unroll
  for (int e=0; e<2; ++e){
    int czt = w*2+e;
    floatx4 acc2 = (floatx4){0.f,0.f,0.f,0.f};
    #pragma unroll 8
    for (int ks=0; ks<32; ++ks){
      short8 pa = *(const short8*)(P + (((ln15>>2)*32 + ks)<<7) + (ln15&3)*32 + quad*8);
      short8 wf = *(const short8*)(woutb + (size_t)(czt*16+ln15)*1024 + ks*32 + quad*8);
      acc2 = __builtin_amdgcn_mfma_f32_16x16x32_bf16(pa, wf, acc2, 0, 0, 0);
    }
    #pragma unroll
    for (int r2=0;r2<4;++r2){
      int p = quad*4+r2, ic = p>>2, jc = p&3;
      int i = i0+ic, j = j0+jc;
      float nv = num[(size_t)i*N_DIM+j];
      size_t zi = ((size_t)i*N_DIM + j)*CZ + czt*16 + ln15;
      zout[zi] = zin[zi] + acc2[r2]*(1.0f/nv) + bout[czt*16+ln15];
    }
  }
}

extern "C" void kernel_launch(void* const* d_in, const int* in_sizes, int n_in,
                              void* d_out, int out_size, void* d_ws, size_t ws_size,
                              hipStream_t stream)
{
  const float* z    = (const float*)d_in[0];
  const float* m    = (const float*)d_in[1];
  const float* tm   = (const float*)d_in[2];
  const float* mask = (const float*)d_in[3];
  const float* lnzg = (const float*)d_in[4];
  const float* lnzb = (const float*)d_in[5];
  const float* wz   = (const float*)d_in[6];
  const float* lnmg = (const float*)d_in[7];
  const float* lnmb = (const float*)d_in[8];
  const float* wm   = (const float*)d_in[9];
  const float* wg   = (const float*)d_in[10];
  const float* wo   = (const float*)d_in[11];
  const float* lntg = (const float*)d_in[12];
  const float* lntb = (const float*)d_in[13];
  const float* fc1  = (const float*)d_in[14];
  const float* fc2  = (const float*)d_in[15];
  const float* fc3  = (const float*)d_in[16];
  const float* lnog = (const float*)d_in[17];
  const float* lnob = (const float*)d_in[18];
  const float* wa   = (const float*)d_in[19];
  const float* wb   = (const float*)d_in[20];
  const float* wout = (const float*)d_in[21];
  const float* bout = (const float*)d_in[22];

  float* zout = (float*)d_out;
  float* mout = zout + (size_t)N_DIM*N_DIM*CZ;

  // z-region of d_out doubles as scratch for buffers dead before k8 writes z:
  char* zs = (char*)d_out;
  unsigned short* mn     = (unsigned short*)zs;               // 50,331,648 B
  float*          logits = (float*)(zs + 50331648);           //  4,718,592 B
  unsigned short* watt   = (unsigned short*)(zs + 55050240);  //  2,359,296 B
  unsigned short* W      = (unsigned short*)(zs + 57409536);  // bf16 weights (dead before k8)
  unsigned short* wgb  = W;          // 16384
  unsigned short* wob  = W + 16384;  // 16384
  unsigned short* fc1b = W + 32768;  // 16384
  unsigned short* fc2b = W + 49152;  // 16384
  unsigned short* fc3b = W + 65536;  // 16384
  unsigned short* wabb = W + 81920;  //  4096

  char* ws = (char*)d_ws;
  unsigned short* v2    = (unsigned short*)ws;                // 201,326,592 B
  unsigned short* o2    = (unsigned short*)(ws + 201326592);  // 201,326,592 B
  float*          num   = (float*)(ws + 402653184);           //     589,824 B
  unsigned short* woutb = (unsigned short*)(ws + 403243008);  //     262,144 B
  unsigned short* a2 = v2;                                    // alias: v2 dead after k4
  unsigned short* b2 = v2 + (size_t)MO*S_DIM;

  kcvt<<<64, 256, 0, stream>>>(wg,  wgb,  16384);
  kcvt<<<64, 256, 0, stream>>>(wo,  wob,  16384);
  kcvt<<<64, 256, 0, stream>>>(fc1, fc1b, 16384);
  kcvt<<<64, 256, 0, stream>>>(fc2, fc2b, 16384);
  kcvt<<<64, 256, 0, stream>>>(fc3, fc3b, 16384);
  kcvt<<<8,  256, 0, stream>>>(wa,  wabb, 2048);
  kcvt<<<8,  256, 0, stream>>>(wb,  wabb+2048, 2048);
  kcvt<<<512,256, 0, stream>>>(wout, woutb, 131072);

  k1_logits  <<<36864, 256, 0, stream>>>(z, tm, lnzg, lnzb, wz, logits);
  k2_softmax <<<768, 256, 0, stream>>>(logits, watt);
  k3_lnm_v   <<<dim3(24,1024), 256, 0, stream>>>(m, lnmg, lnmb, wm, mn, v2);
  k7_num     <<<dim3(24,24), 256, 0, stream>>>(mask, num);
  k4_attn    <<<dim3(256,3,8), 256, 0, stream>>>(watt, v2, o2);
  k5m        <<<dim3(8,384), 256, 0, stream>>>(m, mn, o2, wgb, wob, mout);
  k6m        <<<dim3(8,384), 256, 0, stream>>>(mout, mask, lntg, lntb, fc1b, fc2b, fc3b,
                                               lnog, lnob, wabb, a2, b2);
  k8_outer   <<<dim3(96,96), 256, 0, stream>>>(a2, b2, woutb, num, z, bout, zout);
}

// Round 2
// 1810.191 us; speedup vs baseline: 1.1261x; 1.0108x over previous
//
#include <hip/hip_runtime.h>

#define S_DIM 1024
#define N_DIM 384
#define CZ    128
#define CM    64
#define H_DIM 8
#define CH    32
#define COPM  32
#define HID   256
#define SD    32768   // S_DIM*CH
#define MO    12288   // N_DIM*COPM
#define LDSW  72      // padded LDS row stride (ushorts), 144B = 16B-aligned

typedef __attribute__((ext_vector_type(8))) short  short8;
typedef __attribute__((ext_vector_type(4))) float  floatx4;

__device__ __forceinline__ float bf2f(unsigned short u){
  union { unsigned int u; float f; } v; v.u = ((unsigned int)u)<<16; return v.f;
}
__device__ __forceinline__ unsigned short f2bf(float f){
  union { float f; unsigned int u; } v; v.f = f;
  return (unsigned short)((v.u + 0x7fffu + ((v.u>>16)&1u)) >> 16);
}
__device__ __forceinline__ float red64(float x){
  #pragma unroll
  for (int off=1; off<64; off<<=1) x += __shfl_xor(x, off, 64);
  return x;
}
__device__ __forceinline__ float red16(float x){
  #pragma unroll
  for (int off=1; off<16; off<<=1) x += __shfl_xor(x, off, 64);
  return x;
}
__device__ __forceinline__ void gload16(const void* g, void* l){
  __builtin_amdgcn_global_load_lds((__attribute__((address_space(1))) void*)(g),
                                   (__attribute__((address_space(3))) void*)(l), 16, 0, 0);
}
// raw barrier + compiler memory fence (does NOT auto-drain vmcnt like __syncthreads)
__device__ __forceinline__ void barrier_nodrain(){
  asm volatile("" ::: "memory");
  __builtin_amdgcn_s_barrier();
  asm volatile("" ::: "memory");
}
__device__ __forceinline__ void vmwait4(){ asm volatile("s_waitcnt vmcnt(4)" ::: "memory"); }
__device__ __forceinline__ void vmwait0(){ asm volatile("s_waitcnt vmcnt(0)" ::: "memory"); }

// ---------------- generic fp32 -> bf16 convert ----------------
__global__ void kcvt(const float* __restrict__ w, unsigned short* __restrict__ o, int n){
  int i = blockIdx.x*256 + threadIdx.x;
  if (i < n) o[i] = f2bf(w[i]);
}

// ---------------- K1: logits[h][i][j] = LN(z)@wz^T + mask ----------------
__global__ __launch_bounds__(256) void k1_logits(
    const float* __restrict__ z, const float* __restrict__ tm,
    const float* __restrict__ g, const float* __restrict__ b,
    const float* __restrict__ wz, float* __restrict__ logits)
{
  int idx  = blockIdx.x*4 + (threadIdx.x>>6);      // (i,j) flat, 147456
  int lane = threadIdx.x & 63;
  const float* zp = z + (size_t)idx*CZ;
  float x0 = zp[lane], x1 = zp[lane+64];
  float mu = red64(x0+x1) * (1.0f/128.0f);
  float d0 = x0-mu, d1 = x1-mu;
  float var = red64(d0*d0 + d1*d1) * (1.0f/128.0f);
  float rs = rsqrtf(var + 1e-5f);
  float y0 = d0*rs*g[lane]    + b[lane];
  float y1 = d1*rs*g[lane+64] + b[lane+64];
  float mterm = (1.0f - tm[idx]) * (-1e6f);
  #pragma unroll
  for (int h=0; h<H_DIM; ++h){
    float p = y0*wz[h*CZ+lane] + y1*wz[h*CZ+64+lane];
    p = red64(p);
    if (lane==0) logits[(size_t)h*N_DIM*N_DIM + idx] = p + mterm;
  }
}

// ---------------- K2: softmax rows -> w_att bf16 ----------------
__global__ __launch_bounds__(256) void k2_softmax(
    const float* __restrict__ logits, unsigned short* __restrict__ watt)
{
  int row  = blockIdx.x*4 + (threadIdx.x>>6);      // 3072 rows (h*384+i)
  int lane = threadIdx.x & 63;
  const float* p = logits + (size_t)row*N_DIM;
  float v[6]; float mx = -3.4e38f;
  #pragma unroll
  for (int e=0;e<6;++e){ v[e] = p[lane + e*64]; mx = fmaxf(mx, v[e]); }
  #pragma unroll
  for (int off=1; off<64; off<<=1) mx = fmaxf(mx, __shfl_xor(mx, off, 64));
  float sum = 0.f;
  #pragma unroll
  for (int e=0;e<6;++e){ v[e] = __expf(v[e]-mx); sum += v[e]; }
  sum = red64(sum);
  float inv = 1.0f/sum;
  #pragma unroll
  for (int e=0;e<6;++e) watt[(size_t)row*N_DIM + lane + e*64] = f2bf(v[e]*inv);
}

// ---------------- K3: mn = LN(m) (bf16), v2[h][(s,d)][j] = mn@wm^T ----------------
__global__ __launch_bounds__(256) void k3_lnm_v(
    const float* __restrict__ m, const float* __restrict__ g, const float* __restrict__ b,
    const float* __restrict__ wm, unsigned short* __restrict__ mn, unsigned short* __restrict__ v2)
{
  __shared__ float mnL[16*64];
  int s = blockIdx.y, j0 = blockIdx.x*16, t = threadIdx.x;
  {
    int r = t>>4, q = t&15;
    size_t row = (size_t)s*N_DIM + j0 + r;
    float4 x = *(const float4*)(m + row*CM + q*4);
    float mu = red16(x.x+x.y+x.z+x.w) * (1.0f/64.0f);
    float4 d = {x.x-mu, x.y-mu, x.z-mu, x.w-mu};
    float var = red16(d.x*d.x+d.y*d.y+d.z*d.z+d.w*d.w) * (1.0f/64.0f);
    float rs = rsqrtf(var + 1e-5f);
    float4 y;
    y.x = d.x*rs*g[q*4+0] + b[q*4+0];
    y.y = d.y*rs*g[q*4+1] + b[q*4+1];
    y.z = d.z*rs*g[q*4+2] + b[q*4+2];
    y.w = d.w*rs*g[q*4+3] + b[q*4+3];
    mnL[r*64+q*4+0]=y.x; mnL[r*64+q*4+1]=y.y; mnL[r*64+q*4+2]=y.z; mnL[r*64+q*4+3]=y.w;
    ushort4 u4 = {f2bf(y.x), f2bf(y.y), f2bf(y.z), f2bf(y.w)};
    *(ushort4*)(mn + row*CM + q*4) = u4;
  }
  __syncthreads();
  float acc[16];
  #pragma unroll
  for (int r=0;r<16;++r) acc[r]=0.f;
  const float4* wm4  = (const float4*)wm;
  const float4* mnL4 = (const float4*)mnL;
  #pragma unroll 4
  for (int c4=0;c4<16;++c4){
    float4 w = wm4[t*16 + c4];
    #pragma unroll
    for (int r=0;r<16;++r){
      float4 x = mnL4[r*16 + c4];
      acc[r] += x.x*w.x + x.y*w.y + x.z*w.z + x.w*w.w;
    }
  }
  int h = t>>5, d2 = t&31;
  short8 p0, p1;
  #pragma unroll
  for (int e=0;e<8;++e){ p0[e] = (short)f2bf(acc[e]); p1[e] = (short)f2bf(acc[8+e]); }
  unsigned short* dst = v2 + ((size_t)h*SD + (size_t)s*CH + d2)*N_DIM + j0;
  *(short8*)dst       = p0;
  *(short8*)(dst + 8) = p1;
}

// ---------------- K7: num[i][j] = max(1, sum_s mask[s,i]*mask[s,j]) ----------------
__global__ __launch_bounds__(256) void k7_num(
    const float* __restrict__ mask, float* __restrict__ num)
{
  __shared__ float mA[64*16], mB[64*16];
  int i0 = blockIdx.y*16, j0 = blockIdx.x*16, t = threadIdx.x;
  int ti = t>>4, tj = t&15;
  float acc = 0.f;
  for (int s0=0; s0<S_DIM; s0+=64){
    #pragma unroll
    for (int k=0;k<4;++k){
      int idx = t + k*256; int ss = idx>>4, c = idx&15;
      mA[idx] = mask[(size_t)(s0+ss)*N_DIM + i0 + c];
      mB[idx] = mask[(size_t)(s0+ss)*N_DIM + j0 + c];
    }
    __syncthreads();
    #pragma unroll 8
    for (int ss=0; ss<64; ++ss) acc += mA[ss*16+ti] * mB[ss*16+tj];
    __syncthreads();
  }
  num[(size_t)(i0+ti)*N_DIM + j0+tj] = fmaxf(acc, 1.0f);
}

// ---------------- shared 128x128 A*B^T core (m97 pattern, XOR-swizzled LDS) ----------------
// (still used by k4_attn)
__device__ __forceinline__ void gemm_bt_core(
    const unsigned short* __restrict__ A, const unsigned short* __restrict__ B,
    int lda, int ldb, int K,
    unsigned short* As, unsigned short* Bs, floatx4 acc[4][4],
    int wr, int wc, int ln15, int quad)
{
  int t = threadIdx.x;
  for (int k0=0; k0<K; k0+=64){
    #pragma unroll
    for (int it=0; it<4; ++it){
      int ch = it*256 + t;                  // 1024 chunks of 16B per operand
      int row = ch>>3, slot = ch&7;
      int koff = (slot ^ (row&7))*8;        // inverse-swizzled global source
      gload16(A + (size_t)row*lda + k0 + koff, As + ch*8);
      gload16(B + (size_t)row*ldb + k0 + koff, Bs + ch*8);
    }
    __syncthreads();
    #pragma unroll
    for (int kk=0; kk<2; ++kk){
      int sw = (((kk<<2) | quad) ^ (ln15 & 7)) << 3;   // swizzled 16B slot (ushorts)
      short8 af[4], bfr[4];
      #pragma unroll
      for (int x=0;x<4;++x) af[x]  = *(const short8*)(As + ((wr + x*16 + ln15)<<6) + sw);
      #pragma unroll
      for (int x=0;x<4;++x) bfr[x] = *(const short8*)(Bs + ((wc + x*16 + ln15)<<6) + sw);
      #pragma unroll
      for (int ti=0;ti<4;++ti)
        #pragma unroll
        for (int tj=0;tj<4;++tj)
          acc[ti][tj] = __builtin_amdgcn_mfma_f32_16x16x32_bf16(af[ti], bfr[tj], acc[ti][tj], 0, 0, 0);
    }
    __syncthreads();
  }
}

// ---------------- K4: per-head attention o2[h][i][(s,d)] = att @ v2^T ----------------
__global__ __launch_bounds__(256) void k4_attn(
    const unsigned short* __restrict__ watt, const unsigned short* __restrict__ v2,
    unsigned short* __restrict__ o2)
{
  __shared__ unsigned short smem[16384];
  int t = threadIdx.x, lane = t&63, w = t>>6;
  int ln15 = lane&15, quad = lane>>4;
  int wr = (w>>1)*64, wc = (w&1)*64;
  int nb = blockIdx.x, mb = blockIdx.y, h = blockIdx.z;
  const unsigned short* A = watt + (size_t)h*N_DIM*N_DIM + (size_t)(mb*128)*N_DIM;
  const unsigned short* B = v2 + ((size_t)h*SD + (size_t)nb*128)*N_DIM;
  floatx4 acc[4][4];
  #pragma unroll
  for (int ti=0;ti<4;++ti)
    #pragma unroll
    for (int tj=0;tj<4;++tj) acc[ti][tj] = (floatx4){0.f,0.f,0.f,0.f};
  gemm_bt_core(A, B, N_DIM, N_DIM, N_DIM, smem, smem+8192, acc, wr, wc, ln15, quad);
  unsigned short* C = o2 + ((size_t)h*N_DIM + mb*128)*SD + nb*128;
  #pragma unroll
  for (int ti=0;ti<4;++ti)
    #pragma unroll
    for (int tj=0;tj<4;++tj)
      #pragma unroll
      for (int r=0;r<4;++r)
        C[(size_t)(wr+ti*16+quad*4+r)*SD + wc + tj*16 + ln15] = f2bf(acc[ti][tj][r]);
}

// ---------------- K5m: MFMA PWA update: m1 = m + (sigmoid(mn@wg^T) * o) @ wo^T ----------------
__global__ __launch_bounds__(256) void k5m(
    const float* __restrict__ m_in, const unsigned short* __restrict__ mn,
    const unsigned short* __restrict__ o2,
    const unsigned short* __restrict__ wgb, const unsigned short* __restrict__ wob,
    float* __restrict__ m1_out)
{
  __shared__ unsigned short tA[128*LDSW];
  __shared__ unsigned short uC[128*LDSW];
  int i = blockIdx.y, s0 = blockIdx.x*128, t = threadIdx.x;
  int lane = t&63, w = t>>6, ln15 = lane&15, quad = lane>>4;
  int wr = (w>>1)*64, wc2 = (w&1)*32;

  { // stage mn rows (s0+r, i) -> tA
    int r = t>>1, hf = t&1;
    const unsigned short* src = mn + (((size_t)(s0+r))*N_DIM + i)*CM + hf*32;
    #pragma unroll
    for (int e=0;e<4;++e)
      *(short8*)(tA + r*LDSW + hf*32 + e*8) = *(const short8*)(src + e*8);
  }
  __syncthreads();

  short8 af[4][2];
  #pragma unroll
  for (int x=0;x<4;++x)
    #pragma unroll
    for (int kk=0;kk<2;++kk)
      af[x][kk] = *(const short8*)(tA + (wr + x*16 + ln15)*LDSW + kk*32 + quad*8);

  floatx4 mAcc[4][2];
  #pragma unroll
  for (int x=0;x<4;++x){ mAcc[x][0]=(floatx4){0,0,0,0}; mAcc[x][1]=(floatx4){0,0,0,0}; }

  for (int hc=0; hc<4; ++hc){
    floatx4 gA[4][2];
    #pragma unroll
    for (int x=0;x<4;++x){ gA[x][0]=(floatx4){0,0,0,0}; gA[x][1]=(floatx4){0,0,0,0}; }
    short8 bg[2][2];
    #pragma unroll
    for (int xj=0;xj<2;++xj)
      #pragma unroll
      for (int kk=0;kk<2;++kk)
        bg[xj][kk] = *(const short8*)(wgb + (hc*64 + wc2 + xj*16 + ln15)*CM + kk*32 + quad*8);
    #pragma unroll
    for (int kk=0;kk<2;++kk)
      #pragma unroll
      for (int x=0;x<4;++x)
        #pragma unroll
        for (int xj=0;xj<2;++xj)
          gA[x][xj] = __builtin_amdgcn_mfma_f32_16x16x32_bf16(af[x][kk], bg[xj][kk], gA[x][xj], 0,0,0);
    __syncthreads();  // prev chunk's uC reads complete
    #pragma unroll
    for (int x=0;x<4;++x)
      #pragma unroll
      for (int xj=0;xj<2;++xj)
        #pragma unroll
        for (int r=0;r<4;++r){
          int s = wr + x*16 + quad*4 + r, c = wc2 + xj*16 + ln15;
          int hd = hc*64 + c, h = hd>>5, d = hd&31;
          float gv = 1.f/(1.f+__expf(-gA[x][xj][r]));
          float ov = bf2f(o2[((size_t)(h*N_DIM + i))*SD + (size_t)(s0+s)*CH + d]);
          uC[s*LDSW + c] = f2bf(gv*ov);
        }
    __syncthreads();
    short8 au[4][2], bo[2][2];
    #pragma unroll
    for (int x=0;x<4;++x)
      #pragma unroll
      for (int kk=0;kk<2;++kk)
        au[x][kk] = *(const short8*)(uC + (wr + x*16 + ln15)*LDSW + kk*32 + quad*8);
    #pragma unroll
    for (int xj=0;xj<2;++xj)
      #pragma unroll
      for (int kk=0;kk<2;++kk)
        bo[xj][kk] = *(const short8*)(wob + (wc2 + xj*16 + ln15)*HID + hc*64 + kk*32 + quad*8);
    #pragma unroll
    for (int kk=0;kk<2;++kk)
      #pragma unroll
      for (int x=0;x<4;++x)
        #pragma unroll
        for (int xj=0;xj<2;++xj)
          mAcc[x][xj] = __builtin_amdgcn_mfma_f32_16x16x32_bf16(au[x][kk], bo[xj][kk], mAcc[x][xj], 0,0,0);
  }
  #pragma unroll
  for (int x=0;x<4;++x)
    #pragma unroll
    for (int xj=0;xj<2;++xj)
      #pragma unroll
      for (int r=0;r<4;++r){
        int s = wr + x*16 + quad*4 + r, c = wc2 + xj*16 + ln15;
        size_t gi = (((size_t)(s0+s))*N_DIM + i)*CM + c;
        m1_out[gi] = m_in[gi] + mAcc[x][xj][r];
      }
}

// ---------------- K6m: MFMA SwiGLU transition + LN + a/b projections ----------------
__global__ __launch_bounds__(256) void k6m(
    float* __restrict__ m_io, const float* __restrict__ mask,
    const float* __restrict__ lntg, const float* __restrict__ lntb,
    const unsigned short* __restrict__ fc1b, const unsigned short* __restrict__ fc2b,
    const unsigned short* __restrict__ fc3b,
    const float* __restrict__ lnog, const float* __restrict__ lnob,
    const unsigned short* __restrict__ wabb,
    unsigned short* __restrict__ a2g, unsigned short* __restrict__ b2g)
{
  __shared__ unsigned short tA[128*LDSW];
  __shared__ unsigned short uC[128*LDSW];
  __shared__ float maskL[128];
  int i = blockIdx.y, s0 = blockIdx.x*128, t = threadIdx.x;
  int lane = t&63, w = t>>6, ln15 = lane&15, quad = lane>>4;
  int wr = (w>>1)*64, wc2 = (w&1)*32;

  { // LN1 of m1 rows -> tA (bf16)
    int r = t>>1, hf = t&1;
    const float4* src = (const float4*)(m_io + (((size_t)(s0+r))*N_DIM + i)*CM + hf*32);
    float xv[32];
    #pragma unroll
    for (int e=0;e<8;++e){
      float4 x = src[e];
      xv[e*4+0]=x.x; xv[e*4+1]=x.y; xv[e*4+2]=x.z; xv[e*4+3]=x.w;
    }
    float sm = 0.f;
    #pragma unroll
    for (int e=0;e<32;++e) sm += xv[e];
    sm += __shfl_xor(sm, 1, 64);
    float mu = sm * (1.0f/64.0f);
    float vr = 0.f;
    #pragma unroll
    for (int e=0;e<32;++e){ float d = xv[e]-mu; vr += d*d; }
    vr += __shfl_xor(vr, 1, 64);
    float rs = rsqrtf(vr*(1.0f/64.0f) + 1e-5f);
    #pragma unroll
    for (int e=0;e<8;++e){
      ushort4 pk;
      pk.x = f2bf((xv[e*4+0]-mu)*rs*lntg[hf*32+e*4+0] + lntb[hf*32+e*4+0]);
      pk.y = f2bf((xv[e*4+1]-mu)*rs*lntg[hf*32+e*4+1] + lntb[hf*32+e*4+1]);
      pk.z = f2bf((xv[e*4+2]-mu)*rs*lntg[hf*32+e*4+2] + lntb[hf*32+e*4+2]);
      pk.w = f2bf((xv[e*4+3]-mu)*rs*lntg[hf*32+e*4+3] + lntb[hf*32+e*4+3]);
      *(ushort4*)(tA + r*LDSW + hf*32 + e*4) = pk;
    }
    if (t < 128) maskL[t] = mask[(size_t)(s0+t)*N_DIM + i];
  }
  __syncthreads();

  short8 af[4][2];
  #pragma unroll
  for (int x=0;x<4;++x)
    #pragma unroll
    for (int kk=0;kk<2;++kk)
      af[x][kk] = *(const short8*)(tA + (wr + x*16 + ln15)*LDSW + kk*32 + quad*8);

  floatx4 mAcc[4][2];
  #pragma unroll
  for (int x=0;x<4;++x){ mAcc[x][0]=(floatx4){0,0,0,0}; mAcc[x][1]=(floatx4){0,0,0,0}; }

  for (int hc=0; hc<4; ++hc){
    floatx4 h1A[4][2], h2A[4][2];
    #pragma unroll
    for (int x=0;x<4;++x){
      h1A[x][0]=(floatx4){0,0,0,0}; h1A[x][1]=(floatx4){0,0,0,0};
      h2A[x][0]=(floatx4){0,0,0,0}; h2A[x][1]=(floatx4){0,0,0,0};
    }
    short8 b1[2][2], b2[2][2];
    #pragma unroll
    for (int xj=0;xj<2;++xj)
      #pragma unroll
      for (int kk=0;kk<2;++kk){
        int hrow = hc*64 + wc2 + xj*16 + ln15;
        b1[xj][kk] = *(const short8*)(fc1b + hrow*CM + kk*32 + quad*8);
        b2[xj][kk] = *(const short8*)(fc2b + hrow*CM + kk*32 + quad*8);
      }
    #pragma unroll
    for (int kk=0;kk<2;++kk)
      #pragma unroll
      for (int x=0;x<4;++x)
        #pragma unroll
        for (int xj=0;xj<2;++xj){
          h1A[x][xj] = __builtin_amdgcn_mfma_f32_16x16x32_bf16(af[x][kk], b1[xj][kk], h1A[x][xj], 0,0,0);
          h2A[x][xj] = __builtin_amdgcn_mfma_f32_16x16x32_bf16(af[x][kk], b2[xj][kk], h2A[x][xj], 0,0,0);
        }
    __syncthreads();  // prev chunk's uC reads complete
    #pragma unroll
    for (int x=0;x<4;++x)
      #pragma unroll
      for (int xj=0;xj<2;++xj)
        #pragma unroll
        for (int r=0;r<4;++r){
          int s = wr + x*16 + quad*4 + r, c = wc2 + xj*16 + ln15;
          float hv = h1A[x][xj][r];
          float u = hv/(1.f+__expf(-hv)) * h2A[x][xj][r];
          uC[s*LDSW + c] = f2bf(u);
        }
    __syncthreads();
    short8 au[4][2], b3[2][2];
    #pragma unroll
    for (int x=0;x<4;++x)
      #pragma unroll
      for (int kk=0;kk<2;++kk)
        au[x][kk] = *(const short8*)(uC + (wr + x*16 + ln15)*LDSW + kk*32 + quad*8);
    #pragma unroll
    for (int xj=0;xj<2;++xj)
      #pragma unroll
      for (int kk=0;kk<2;++kk)
        b3[xj][kk] = *(const short8*)(fc3b + (wc2 + xj*16 + ln15)*HID + hc*64 + kk*32 + quad*8);
    #pragma unroll
    for (int kk=0;kk<2;++kk)
      #pragma unroll
      for (int x=0;x<4;++x)
        #pragma unroll
        for (int xj=0;xj<2;++xj)
          mAcc[x][xj] = __builtin_amdgcn_mfma_f32_16x16x32_bf16(au[x][kk], b3[xj][kk], mAcc[x][xj], 0,0,0);
  }
  __syncthreads();  // all uC/tA reads complete

  // m2 = m1 + mAcc -> global (fp32) + tA (bf16)
  #pragma unroll
  for (int x=0;x<4;++x)
    #pragma unroll
    for (int xj=0;xj<2;++xj)
      #pragma unroll
      for (int r=0;r<4;++r){
        int s = wr + x*16 + quad*4 + r, c = wc2 + xj*16 + ln15;
        size_t gi = (((size_t)(s0+s))*N_DIM + i)*CM + c;
        float m2v = m_io[gi] + mAcc[x][xj][r];
        m_io[gi] = m2v;
        tA[s*LDSW + c] = f2bf(m2v);
      }
  __syncthreads();

  { // LN2 from tA -> mo in uC
    int r = t>>1, hf = t&1;
    float xv[32];
    #pragma unroll
    for (int e=0;e<32;++e) xv[e] = bf2f(tA[r*LDSW + hf*32 + e]);
    float sm = 0.f;
    #pragma unroll
    for (int e=0;e<32;++e) sm += xv[e];
    sm += __shfl_xor(sm, 1, 64);
    float mu = sm * (1.0f/64.0f);
    float vr = 0.f;
    #pragma unroll
    for (int e=0;e<32;++e){ float d = xv[e]-mu; vr += d*d; }
    vr += __shfl_xor(vr, 1, 64);
    float rs = rsqrtf(vr*(1.0f/64.0f) + 1e-5f);
    #pragma unroll
    for (int e=0;e<8;++e){
      ushort4 pk;
      pk.x = f2bf((xv[e*4+0]-mu)*rs*lnog[hf*32+e*4+0] + lnob[hf*32+e*4+0]);
      pk.y = f2bf((xv[e*4+1]-mu)*rs*lnog[hf*32+e*4+1] + lnob[hf*32+e*4+1]);
      pk.z = f2bf((xv[e*4+2]-mu)*rs*lnog[hf*32+e*4+2] + lnob[hf*32+e*4+2]);
      pk.w = f2bf((xv[e*4+3]-mu)*rs*lnog[hf*32+e*4+3] + lnob[hf*32+e*4+3]);
      *(ushort4*)(uC + r*LDSW + hf*32 + e*4) = pk;
    }
  }
  __syncthreads();

  // GEMM3: mo @ [wa;wb]^T (K=64), masked transposed store
  floatx4 ab[4][2];
  #pragma unroll
  for (int x=0;x<4;++x){ ab[x][0]=(floatx4){0,0,0,0}; ab[x][1]=(floatx4){0,0,0,0}; }
  short8 am[4][2], bw[2][2];
  #pragma unroll
  for (int x=0;x<4;++x)
    #pragma unroll
    for (int kk=0;kk<2;++kk)
      am[x][kk] = *(const short8*)(uC + (wr + x*16 + ln15)*LDSW + kk*32 + quad*8);
  #pragma unroll
  for (int xj=0;xj<2;++xj)
    #pragma unroll
    for (int kk=0;kk<2;++kk)
      bw[xj][kk] = *(const short8*)(wabb + (wc2 + xj*16 + ln15)*CM + kk*32 + quad*8);
  #pragma unroll
  for (int kk=0;kk<2;++kk)
    #pragma unroll
    for (int x=0;x<4;++x)
      #pragma unroll
      for (int xj=0;xj<2;++xj)
        ab[x][xj] = __builtin_amdgcn_mfma_f32_16x16x32_bf16(am[x][kk], bw[xj][kk], ab[x][xj], 0,0,0);
  #pragma unroll
  for (int x=0;x<4;++x)
    #pragma unroll
    for (int xj=0;xj<2;++xj){
      int c = wc2 + xj*16 + ln15;
      int sbase = wr + x*16 + quad*4;
      ushort4 pk;
      #pragma unroll
      for (int r=0;r<4;++r) pk[r] = f2bf(ab[x][xj][r] * maskL[sbase+r]);
      unsigned short* dst = (c < 32)
        ? (a2g + ((size_t)i*COPM + c)*S_DIM + s0 + sbase)
        : (b2g + ((size_t)i*COPM + (c-32))*S_DIM + s0 + sbase);
      *(ushort4*)dst = pk;
    }
}

// ---------------- K8: 256x256-tile outer-product GEMM, counted-vmcnt pipeline ----------------
// BM=BN=256, BK=32, 512 thr = 8 waves (2M x 4N), wave tile 128x64.
// LDS 64KB: As[2][256*32] | Bs[2][256*32]. Double-buffered at K-tile granularity:
// stage tile t+2 right after the barrier retiring tile t's reads; vmcnt(4) keeps
// tile t+2's 4 loads in flight across the barrier while guaranteeing tile t+1
// has landed. Raw s_barrier (no auto vmcnt(0) drain). Row stride 64B => fragment
// ds_read_b128 is naturally bank-uniform (no swizzle needed at BK=32).
__device__ __forceinline__ void k8_stage(const unsigned short* Ag, const unsigned short* Bg,
                                         unsigned short* lds, int sel, int kt, int t){
  #pragma unroll
  for (int it=0; it<2; ++it){
    int ch = it*512 + t;
    int row = ch>>2, slot = ch&3;
    size_t goff = (size_t)row*S_DIM + kt*32 + slot*8;
    gload16(Ag + goff, lds + sel*8192 + ch*8);
    gload16(Bg + goff, lds + 16384 + sel*8192 + ch*8);
  }
}

__global__ __launch_bounds__(512, 2) void k8_outer(
    const unsigned short* __restrict__ a2, const unsigned short* __restrict__ b2,
    const unsigned short* __restrict__ woutb, const float* __restrict__ num,
    const float* __restrict__ zin, const float* __restrict__ bout,
    float* __restrict__ zout)
{
  __shared__ unsigned short lds[32768];   // 64KB
  int t = threadIdx.x, lane = t&63, w = t>>6;
  int ln15 = lane&15, quad = lane>>4;
  int wm = w>>2, wn = w&3;
  int wr = wm*128, wcol = wn*64;
  int nb = blockIdx.x, mb = blockIdx.y;
  const unsigned short* Ag = a2 + (size_t)(mb*256)*S_DIM;
  const unsigned short* Bg = b2 + (size_t)(nb*256)*S_DIM;

  floatx4 acc[8][4];
  #pragma unroll
  for (int rf=0; rf<8; ++rf)
    #pragma unroll
    for (int cf=0; cf<4; ++cf) acc[rf][cf] = (floatx4){0.f,0.f,0.f,0.f};

  k8_stage(Ag, Bg, lds, 0, 0, t);
  k8_stage(Ag, Bg, lds, 1, 1, t);
  vmwait4();            // tile 0 landed (tile 1's 4 loads remain in flight)
  barrier_nodrain();

  for (int kt=0; kt<32; ++kt){
    const unsigned short* Ab = lds + (kt&1)*8192;
    const unsigned short* Bb = lds + 16384 + (kt&1)*8192;
    short8 af[8], bf4[4];
    #pragma unroll
    for (int rf=0; rf<8; ++rf)
      af[rf] = *(const short8*)(Ab + (wr + rf*16 + ln15)*32 + quad*8);
    #pragma unroll
    for (int cf=0; cf<4; ++cf)
      bf4[cf] = *(const short8*)(Bb + (wcol + cf*16 + ln15)*32 + quad*8);
    __builtin_amdgcn_s_setprio(1);
    #pragma unroll
    for (int rf=0; rf<8; ++rf)
      #pragma unroll
      for (int cf=0; cf<4; ++cf)
        acc[rf][cf] = __builtin_amdgcn_mfma_f32_16x16x32_bf16(af[rf], bf4[cf], acc[rf][cf], 0, 0, 0);
    __builtin_amdgcn_s_setprio(0);
    barrier_nodrain();                          // all reads of buf (kt&1) retired
    if (kt < 30) k8_stage(Ag, Bg, lds, kt&1, kt+2, t);
    if (kt <= 29) vmwait4();                    // tile kt+1 landed; kt+2 stays in flight
    else if (kt == 30) vmwait0();               // drain tail: tile 31 landed
    barrier_nodrain();                          // collective: next tile ready for all waves
  }

  // ---- fused epilogue: z[i,j,:] += P(i,j,:,:) @ wout^T / num + bout ----
  // P = 256x256 bf16 C-tile, staged into LDS as two 128x256 halves (ih).
  unsigned short* P = lds;                      // [128][256]
  #pragma unroll
  for (int ih=0; ih<2; ++ih){
    if (wm == ih){
      #pragma unroll
      for (int rf=0; rf<8; ++rf)
        #pragma unroll
        for (int cf=0; cf<4; ++cf)
          #pragma unroll
          for (int r=0; r<4; ++r)
            P[(rf*16 + quad*4 + r)*256 + wcol + cf*16 + ln15] = f2bf(acc[rf][cf][r]);
    }
    barrier_nodrain();
    // pairs this pass: p = i_ll*8 + j_ll, i_ll in [0,4) (global i = mb*8+ih*4+i_ll), j_ll in [0,8)
    int prow0 = (ln15>>3)*32;                   // i_ll 0..1 (rf2=0)
    int prow1 = prow0 + 64;                     // i_ll 2..3 (rf2=1)
    int pcol  = (ln15&7)*32 + quad*8;
    const unsigned short* wrow = woutb + (size_t)(w*16 + ln15)*1024 + quad*8;
    floatx4 e0 = (floatx4){0.f,0.f,0.f,0.f};
    floatx4 e1 = (floatx4){0.f,0.f,0.f,0.f};
    #pragma unroll 8
    for (int ks=0; ks<32; ++ks){
      short8 wf  = *(const short8*)(wrow + ks*32);
      short8 pa0 = *(const short8*)(P + (prow0 + ks)*256 + pcol);
      short8 pa1 = *(const short8*)(P + (prow1 + ks)*256 + pcol);
      e0 = __builtin_amdgcn_mfma_f32_16x16x32_bf16(pa0, wf, e0, 0, 0, 0);
      e1 = __builtin_amdgcn_mfma_f32_16x16x32_bf16(pa1, wf, e1, 0, 0, 0);
    }
    #pragma unroll
    for (int rf2=0; rf2<2; ++rf2){
      #pragma unroll
      for (int r=0; r<4; ++r){
        int p = rf2*16 + quad*4 + r;
        int i = mb*8 + ih*4 + (p>>3), j = nb*8 + (p&7);
        float nv = num[(size_t)i*N_DIM + j];
        size_t zi = ((size_t)i*N_DIM + j)*CZ + w*16 + ln15;
        float av = (rf2==0) ? e0[r] : e1[r];
        zout[zi] = zin[zi] + av*(1.0f/nv) + bout[w*16 + ln15];
      }
    }
    barrier_nodrain();                          // P reads done before next pass overwrites
  }
}

extern "C" void kernel_launch(void* const* d_in, const int* in_sizes, int n_in,
                              void* d_out, int out_size, void* d_ws, size_t ws_size,
                              hipStream_t stream)
{
  const float* z    = (const float*)d_in[0];
  const float* m    = (const float*)d_in[1];
  const float* tm   = (const float*)d_in[2];
  const float* mask = (const float*)d_in[3];
  const float* lnzg = (const float*)d_in[4];
  const float* lnzb = (const float*)d_in[5];
  const float* wz   = (const float*)d_in[6];
  const float* lnmg = (const float*)d_in[7];
  const float* lnmb = (const float*)d_in[8];
  const float* wm   = (const float*)d_in[9];
  const float* wg   = (const float*)d_in[10];
  const float* wo   = (const float*)d_in[11];
  const float* lntg = (const float*)d_in[12];
  const float* lntb = (const float*)d_in[13];
  const float* fc1  = (const float*)d_in[14];
  const float* fc2  = (const float*)d_in[15];
  const float* fc3  = (const float*)d_in[16];
  const float* lnog = (const float*)d_in[17];
  const float* lnob = (const float*)d_in[18];
  const float* wa   = (const float*)d_in[19];
  const float* wb   = (const float*)d_in[20];
  const float* wout = (const float*)d_in[21];
  const float* bout = (const float*)d_in[22];

  float* zout = (float*)d_out;
  float* mout = zout + (size_t)N_DIM*N_DIM*CZ;

  // z-region of d_out doubles as scratch for buffers dead before k8 writes z:
  char* zs = (char*)d_out;
  unsigned short* mn     = (unsigned short*)zs;               // 50,331,648 B
  float*          logits = (float*)(zs + 50331648);           //  4,718,592 B
  unsigned short* watt   = (unsigned short*)(zs + 55050240);  //  2,359,296 B
  unsigned short* W      = (unsigned short*)(zs + 57409536);  // bf16 weights (dead before k8)
  unsigned short* wgb  = W;          // 16384
  unsigned short* wob  = W + 16384;  // 16384
  unsigned short* fc1b = W + 32768;  // 16384
  unsigned short* fc2b = W + 49152;  // 16384
  unsigned short* fc3b = W + 65536;  // 16384
  unsigned short* wabb = W + 81920;  //  4096

  char* ws = (char*)d_ws;
  unsigned short* v2    = (unsigned short*)ws;                // 201,326,592 B
  unsigned short* o2    = (unsigned short*)(ws + 201326592);  // 201,326,592 B
  float*          num   = (float*)(ws + 402653184);           //     589,824 B
  unsigned short* woutb = (unsigned short*)(ws + 403243008);  //     262,144 B
  unsigned short* a2 = v2;                                    // alias: v2 dead after k4
  unsigned short* b2 = v2 + (size_t)MO*S_DIM;

  kcvt<<<64, 256, 0, stream>>>(wg,  wgb,  16384);
  kcvt<<<64, 256, 0, stream>>>(wo,  wob,  16384);
  kcvt<<<64, 256, 0, stream>>>(fc1, fc1b, 16384);
  kcvt<<<64, 256, 0, stream>>>(fc2, fc2b, 16384);
  kcvt<<<64, 256, 0, stream>>>(fc3, fc3b, 16384);
  kcvt<<<8,  256, 0, stream>>>(wa,  wabb, 2048);
  kcvt<<<8,  256, 0, stream>>>(wb,  wabb+2048, 2048);
  kcvt<<<512,256, 0, stream>>>(wout, woutb, 131072);

  k1_logits  <<<36864, 256, 0, stream>>>(z, tm, lnzg, lnzb, wz, logits);
  k2_softmax <<<768, 256, 0, stream>>>(logits, watt);
  k3_lnm_v   <<<dim3(24,1024), 256, 0, stream>>>(m, lnmg, lnmb, wm, mn, v2);
  k7_num     <<<dim3(24,24), 256, 0, stream>>>(mask, num);
  k4_attn    <<<dim3(256,3,8), 256, 0, stream>>>(watt, v2, o2);
  k5m        <<<dim3(8,384), 256, 0, stream>>>(m, mn, o2, wgb, wob, mout);
  k6m        <<<dim3(8,384), 256, 0, stream>>>(mout, mask, lntg, lntb, fc1b, fc2b, fc3b,
                                               lnog, lnob, wabb, a2, b2);
  k8_outer   <<<dim3(48,48), 512, 0, stream>>>(a2, b2, woutb, num, z, bout, zout);
}

// Round 3
// 1775.479 us; speedup vs baseline: 1.1481x; 1.0196x over previous
//
#include <hip/hip_runtime.h>

#define S_DIM 1024
#define N_DIM 384
#define CZ    128
#define CM    64
#define H_DIM 8
#define CH    32
#define COPM  32
#define HID   256
#define SD    32768   // S_DIM*CH
#define MO    12288   // N_DIM*COPM
#define LDSW  72      // padded LDS row stride (ushorts), 144B = 16B-aligned

typedef __attribute__((ext_vector_type(8))) short  short8;
typedef __attribute__((ext_vector_type(4))) float  floatx4;

__device__ __forceinline__ float bf2f(unsigned short u){
  union { unsigned int u; float f; } v; v.u = ((unsigned int)u)<<16; return v.f;
}
__device__ __forceinline__ unsigned short f2bf(float f){
  union { float f; unsigned int u; } v; v.f = f;
  return (unsigned short)((v.u + 0x7fffu + ((v.u>>16)&1u)) >> 16);
}
__device__ __forceinline__ float red64(float x){
  #pragma unroll
  for (int off=1; off<64; off<<=1) x += __shfl_xor(x, off, 64);
  return x;
}
__device__ __forceinline__ float red16(float x){
  #pragma unroll
  for (int off=1; off<16; off<<=1) x += __shfl_xor(x, off, 64);
  return x;
}
__device__ __forceinline__ void gload16(const void* g, void* l){
  __builtin_amdgcn_global_load_lds((__attribute__((address_space(1))) void*)(g),
                                   (__attribute__((address_space(3))) void*)(l), 16, 0, 0);
}
// raw barrier + compiler memory fence (does NOT auto-drain vmcnt like __syncthreads)
__device__ __forceinline__ void barrier_nodrain(){
  asm volatile("" ::: "memory");
  __builtin_amdgcn_s_barrier();
  asm volatile("" ::: "memory");
}
__device__ __forceinline__ void vmwait8(){ asm volatile("s_waitcnt vmcnt(8)" ::: "memory"); }
__device__ __forceinline__ void vmwait0(){ asm volatile("s_waitcnt vmcnt(0)" ::: "memory"); }

// ---------------- generic fp32 -> bf16 convert ----------------
__global__ void kcvt(const float* __restrict__ w, unsigned short* __restrict__ o, int n){
  int i = blockIdx.x*256 + threadIdx.x;
  if (i < n) o[i] = f2bf(w[i]);
}

// ---------------- K1: logits[h][i][j] = LN(z)@wz^T + mask ----------------
__global__ __launch_bounds__(256) void k1_logits(
    const float* __restrict__ z, const float* __restrict__ tm,
    const float* __restrict__ g, const float* __restrict__ b,
    const float* __restrict__ wz, float* __restrict__ logits)
{
  int idx  = blockIdx.x*4 + (threadIdx.x>>6);      // (i,j) flat, 147456
  int lane = threadIdx.x & 63;
  const float* zp = z + (size_t)idx*CZ;
  float x0 = zp[lane], x1 = zp[lane+64];
  float mu = red64(x0+x1) * (1.0f/128.0f);
  float d0 = x0-mu, d1 = x1-mu;
  float var = red64(d0*d0 + d1*d1) * (1.0f/128.0f);
  float rs = rsqrtf(var + 1e-5f);
  float y0 = d0*rs*g[lane]    + b[lane];
  float y1 = d1*rs*g[lane+64] + b[lane+64];
  float mterm = (1.0f - tm[idx]) * (-1e6f);
  #pragma unroll
  for (int h=0; h<H_DIM; ++h){
    float p = y0*wz[h*CZ+lane] + y1*wz[h*CZ+64+lane];
    p = red64(p);
    if (lane==0) logits[(size_t)h*N_DIM*N_DIM + idx] = p + mterm;
  }
}

// ---------------- K2: softmax rows -> w_att bf16 ----------------
__global__ __launch_bounds__(256) void k2_softmax(
    const float* __restrict__ logits, unsigned short* __restrict__ watt)
{
  int row  = blockIdx.x*4 + (threadIdx.x>>6);      // 3072 rows (h*384+i)
  int lane = threadIdx.x & 63;
  const float* p = logits + (size_t)row*N_DIM;
  float v[6]; float mx = -3.4e38f;
  #pragma unroll
  for (int e=0;e<6;++e){ v[e] = p[lane + e*64]; mx = fmaxf(mx, v[e]); }
  #pragma unroll
  for (int off=1; off<64; off<<=1) mx = fmaxf(mx, __shfl_xor(mx, off, 64));
  float sum = 0.f;
  #pragma unroll
  for (int e=0;e<6;++e){ v[e] = __expf(v[e]-mx); sum += v[e]; }
  sum = red64(sum);
  float inv = 1.0f/sum;
  #pragma unroll
  for (int e=0;e<6;++e) watt[(size_t)row*N_DIM + lane + e*64] = f2bf(v[e]*inv);
}

// ---------------- K3: mn = LN(m) (bf16), v2[h][(s,d)][j] = mn@wm^T ----------------
__global__ __launch_bounds__(256) void k3_lnm_v(
    const float* __restrict__ m, const float* __restrict__ g, const float* __restrict__ b,
    const float* __restrict__ wm, unsigned short* __restrict__ mn, unsigned short* __restrict__ v2)
{
  __shared__ float mnL[16*64];
  int s = blockIdx.y, j0 = blockIdx.x*16, t = threadIdx.x;
  {
    int r = t>>4, q = t&15;
    size_t row = (size_t)s*N_DIM + j0 + r;
    float4 x = *(const float4*)(m + row*CM + q*4);
    float mu = red16(x.x+x.y+x.z+x.w) * (1.0f/64.0f);
    float4 d = {x.x-mu, x.y-mu, x.z-mu, x.w-mu};
    float var = red16(d.x*d.x+d.y*d.y+d.z*d.z+d.w*d.w) * (1.0f/64.0f);
    float rs = rsqrtf(var + 1e-5f);
    float4 y;
    y.x = d.x*rs*g[q*4+0] + b[q*4+0];
    y.y = d.y*rs*g[q*4+1] + b[q*4+1];
    y.z = d.z*rs*g[q*4+2] + b[q*4+2];
    y.w = d.w*rs*g[q*4+3] + b[q*4+3];
    mnL[r*64+q*4+0]=y.x; mnL[r*64+q*4+1]=y.y; mnL[r*64+q*4+2]=y.z; mnL[r*64+q*4+3]=y.w;
    ushort4 u4 = {f2bf(y.x), f2bf(y.y), f2bf(y.z), f2bf(y.w)};
    *(ushort4*)(mn + row*CM + q*4) = u4;
  }
  __syncthreads();
  float acc[16];
  #pragma unroll
  for (int r=0;r<16;++r) acc[r]=0.f;
  const float4* wm4  = (const float4*)wm;
  const float4* mnL4 = (const float4*)mnL;
  #pragma unroll 4
  for (int c4=0;c4<16;++c4){
    float4 w = wm4[t*16 + c4];
    #pragma unroll
    for (int r=0;r<16;++r){
      float4 x = mnL4[r*16 + c4];
      acc[r] += x.x*w.x + x.y*w.y + x.z*w.z + x.w*w.w;
    }
  }
  int h = t>>5, d2 = t&31;
  short8 p0, p1;
  #pragma unroll
  for (int e=0;e<8;++e){ p0[e] = (short)f2bf(acc[e]); p1[e] = (short)f2bf(acc[8+e]); }
  unsigned short* dst = v2 + ((size_t)h*SD + (size_t)s*CH + d2)*N_DIM + j0;
  *(short8*)dst       = p0;
  *(short8*)(dst + 8) = p1;
}

// ---------------- K7: num[i][j] = max(1, sum_s mask[s,i]*mask[s,j]) ----------------
__global__ __launch_bounds__(256) void k7_num(
    const float* __restrict__ mask, float* __restrict__ num)
{
  __shared__ float mA[64*16], mB[64*16];
  int i0 = blockIdx.y*16, j0 = blockIdx.x*16, t = threadIdx.x;
  int ti = t>>4, tj = t&15;
  float acc = 0.f;
  for (int s0=0; s0<S_DIM; s0+=64){
    #pragma unroll
    for (int k=0;k<4;++k){
      int idx = t + k*256; int ss = idx>>4, c = idx&15;
      mA[idx] = mask[(size_t)(s0+ss)*N_DIM + i0 + c];
      mB[idx] = mask[(size_t)(s0+ss)*N_DIM + j0 + c];
    }
    __syncthreads();
    #pragma unroll 8
    for (int ss=0; ss<64; ++ss) acc += mA[ss*16+ti] * mB[ss*16+tj];
    __syncthreads();
  }
  num[(size_t)(i0+ti)*N_DIM + j0+tj] = fmaxf(acc, 1.0f);
}

// ---------------- shared 128x128 A*B^T core (m97 pattern, XOR-swizzled LDS) ----------------
// (still used by k4_attn)
__device__ __forceinline__ void gemm_bt_core(
    const unsigned short* __restrict__ A, const unsigned short* __restrict__ B,
    int lda, int ldb, int K,
    unsigned short* As, unsigned short* Bs, floatx4 acc[4][4],
    int wr, int wc, int ln15, int quad)
{
  int t = threadIdx.x;
  for (int k0=0; k0<K; k0+=64){
    #pragma unroll
    for (int it=0; it<4; ++it){
      int ch = it*256 + t;                  // 1024 chunks of 16B per operand
      int row = ch>>3, slot = ch&7;
      int koff = (slot ^ (row&7))*8;        // inverse-swizzled global source
      gload16(A + (size_t)row*lda + k0 + koff, As + ch*8);
      gload16(B + (size_t)row*ldb + k0 + koff, Bs + ch*8);
    }
    __syncthreads();
    #pragma unroll
    for (int kk=0; kk<2; ++kk){
      int sw = (((kk<<2) | quad) ^ (ln15 & 7)) << 3;   // swizzled 16B slot (ushorts)
      short8 af[4], bfr[4];
      #pragma unroll
      for (int x=0;x<4;++x) af[x]  = *(const short8*)(As + ((wr + x*16 + ln15)<<6) + sw);
      #pragma unroll
      for (int x=0;x<4;++x) bfr[x] = *(const short8*)(Bs + ((wc + x*16 + ln15)<<6) + sw);
      #pragma unroll
      for (int ti=0;ti<4;++ti)
        #pragma unroll
        for (int tj=0;tj<4;++tj)
          acc[ti][tj] = __builtin_amdgcn_mfma_f32_16x16x32_bf16(af[ti], bfr[tj], acc[ti][tj], 0, 0, 0);
    }
    __syncthreads();
  }
}

// ---------------- K4: per-head attention o2[h][i][(s,d)] = att @ v2^T ----------------
__global__ __launch_bounds__(256) void k4_attn(
    const unsigned short* __restrict__ watt, const unsigned short* __restrict__ v2,
    unsigned short* __restrict__ o2)
{
  __shared__ unsigned short smem[16384];
  int t = threadIdx.x, lane = t&63, w = t>>6;
  int ln15 = lane&15, quad = lane>>4;
  int wr = (w>>1)*64, wc = (w&1)*64;
  int nb = blockIdx.x, mb = blockIdx.y, h = blockIdx.z;
  const unsigned short* A = watt + (size_t)h*N_DIM*N_DIM + (size_t)(mb*128)*N_DIM;
  const unsigned short* B = v2 + ((size_t)h*SD + (size_t)nb*128)*N_DIM;
  floatx4 acc[4][4];
  #pragma unroll
  for (int ti=0;ti<4;++ti)
    #pragma unroll
    for (int tj=0;tj<4;++tj) acc[ti][tj] = (floatx4){0.f,0.f,0.f,0.f};
  gemm_bt_core(A, B, N_DIM, N_DIM, N_DIM, smem, smem+8192, acc, wr, wc, ln15, quad);
  unsigned short* C = o2 + ((size_t)h*N_DIM + mb*128)*SD + nb*128;
  #pragma unroll
  for (int ti=0;ti<4;++ti)
    #pragma unroll
    for (int tj=0;tj<4;++tj)
      #pragma unroll
      for (int r=0;r<4;++r)
        C[(size_t)(wr+ti*16+quad*4+r)*SD + wc + tj*16 + ln15] = f2bf(acc[ti][tj][r]);
}

// ---------------- K5m: MFMA PWA update: m1 = m + (sigmoid(mn@wg^T) * o) @ wo^T ----------------
__global__ __launch_bounds__(256) void k5m(
    const float* __restrict__ m_in, const unsigned short* __restrict__ mn,
    const unsigned short* __restrict__ o2,
    const unsigned short* __restrict__ wgb, const unsigned short* __restrict__ wob,
    float* __restrict__ m1_out)
{
  __shared__ unsigned short tA[128*LDSW];
  __shared__ unsigned short uC[128*LDSW];
  int i = blockIdx.y, s0 = blockIdx.x*128, t = threadIdx.x;
  int lane = t&63, w = t>>6, ln15 = lane&15, quad = lane>>4;
  int wr = (w>>1)*64, wc2 = (w&1)*32;

  { // stage mn rows (s0+r, i) -> tA
    int r = t>>1, hf = t&1;
    const unsigned short* src = mn + (((size_t)(s0+r))*N_DIM + i)*CM + hf*32;
    #pragma unroll
    for (int e=0;e<4;++e)
      *(short8*)(tA + r*LDSW + hf*32 + e*8) = *(const short8*)(src + e*8);
  }
  __syncthreads();

  short8 af[4][2];
  #pragma unroll
  for (int x=0;x<4;++x)
    #pragma unroll
    for (int kk=0;kk<2;++kk)
      af[x][kk] = *(const short8*)(tA + (wr + x*16 + ln15)*LDSW + kk*32 + quad*8);

  floatx4 mAcc[4][2];
  #pragma unroll
  for (int x=0;x<4;++x){ mAcc[x][0]=(floatx4){0,0,0,0}; mAcc[x][1]=(floatx4){0,0,0,0}; }

  for (int hc=0; hc<4; ++hc){
    floatx4 gA[4][2];
    #pragma unroll
    for (int x=0;x<4;++x){ gA[x][0]=(floatx4){0,0,0,0}; gA[x][1]=(floatx4){0,0,0,0}; }
    short8 bg[2][2];
    #pragma unroll
    for (int xj=0;xj<2;++xj)
      #pragma unroll
      for (int kk=0;kk<2;++kk)
        bg[xj][kk] = *(const short8*)(wgb + (hc*64 + wc2 + xj*16 + ln15)*CM + kk*32 + quad*8);
    #pragma unroll
    for (int kk=0;kk<2;++kk)
      #pragma unroll
      for (int x=0;x<4;++x)
        #pragma unroll
        for (int xj=0;xj<2;++xj)
          gA[x][xj] = __builtin_amdgcn_mfma_f32_16x16x32_bf16(af[x][kk], bg[xj][kk], gA[x][xj], 0,0,0);
    __syncthreads();  // prev chunk's uC reads complete
    #pragma unroll
    for (int x=0;x<4;++x)
      #pragma unroll
      for (int xj=0;xj<2;++xj)
        #pragma unroll
        for (int r=0;r<4;++r){
          int s = wr + x*16 + quad*4 + r, c = wc2 + xj*16 + ln15;
          int hd = hc*64 + c, h = hd>>5, d = hd&31;
          float gv = 1.f/(1.f+__expf(-gA[x][xj][r]));
          float ov = bf2f(o2[((size_t)(h*N_DIM + i))*SD + (size_t)(s0+s)*CH + d]);
          uC[s*LDSW + c] = f2bf(gv*ov);
        }
    __syncthreads();
    short8 au[4][2], bo[2][2];
    #pragma unroll
    for (int x=0;x<4;++x)
      #pragma unroll
      for (int kk=0;kk<2;++kk)
        au[x][kk] = *(const short8*)(uC + (wr + x*16 + ln15)*LDSW + kk*32 + quad*8);
    #pragma unroll
    for (int xj=0;xj<2;++xj)
      #pragma unroll
      for (int kk=0;kk<2;++kk)
        bo[xj][kk] = *(const short8*)(wob + (wc2 + xj*16 + ln15)*HID + hc*64 + kk*32 + quad*8);
    #pragma unroll
    for (int kk=0;kk<2;++kk)
      #pragma unroll
      for (int x=0;x<4;++x)
        #pragma unroll
        for (int xj=0;xj<2;++xj)
          mAcc[x][xj] = __builtin_amdgcn_mfma_f32_16x16x32_bf16(au[x][kk], bo[xj][kk], mAcc[x][xj], 0,0,0);
  }
  #pragma unroll
  for (int x=0;x<4;++x)
    #pragma unroll
    for (int xj=0;xj<2;++xj)
      #pragma unroll
      for (int r=0;r<4;++r){
        int s = wr + x*16 + quad*4 + r, c = wc2 + xj*16 + ln15;
        size_t gi = (((size_t)(s0+s))*N_DIM + i)*CM + c;
        m1_out[gi] = m_in[gi] + mAcc[x][xj][r];
      }
}

// ---------------- K6m: MFMA SwiGLU transition + LN + a/b projections ----------------
__global__ __launch_bounds__(256) void k6m(
    float* __restrict__ m_io, const float* __restrict__ mask,
    const float* __restrict__ lntg, const float* __restrict__ lntb,
    const unsigned short* __restrict__ fc1b, const unsigned short* __restrict__ fc2b,
    const unsigned short* __restrict__ fc3b,
    const float* __restrict__ lnog, const float* __restrict__ lnob,
    const unsigned short* __restrict__ wabb,
    unsigned short* __restrict__ a2g, unsigned short* __restrict__ b2g)
{
  __shared__ unsigned short tA[128*LDSW];
  __shared__ unsigned short uC[128*LDSW];
  __shared__ float maskL[128];
  int i = blockIdx.y, s0 = blockIdx.x*128, t = threadIdx.x;
  int lane = t&63, w = t>>6, ln15 = lane&15, quad = lane>>4;
  int wr = (w>>1)*64, wc2 = (w&1)*32;

  { // LN1 of m1 rows -> tA (bf16)
    int r = t>>1, hf = t&1;
    const float4* src = (const float4*)(m_io + (((size_t)(s0+r))*N_DIM + i)*CM + hf*32);
    float xv[32];
    #pragma unroll
    for (int e=0;e<8;++e){
      float4 x = src[e];
      xv[e*4+0]=x.x; xv[e*4+1]=x.y; xv[e*4+2]=x.z; xv[e*4+3]=x.w;
    }
    float sm = 0.f;
    #pragma unroll
    for (int e=0;e<32;++e) sm += xv[e];
    sm += __shfl_xor(sm, 1, 64);
    float mu = sm * (1.0f/64.0f);
    float vr = 0.f;
    #pragma unroll
    for (int e=0;e<32;++e){ float d = xv[e]-mu; vr += d*d; }
    vr += __shfl_xor(vr, 1, 64);
    float rs = rsqrtf(vr*(1.0f/64.0f) + 1e-5f);
    #pragma unroll
    for (int e=0;e<8;++e){
      ushort4 pk;
      pk.x = f2bf((xv[e*4+0]-mu)*rs*lntg[hf*32+e*4+0] + lntb[hf*32+e*4+0]);
      pk.y = f2bf((xv[e*4+1]-mu)*rs*lntg[hf*32+e*4+1] + lntb[hf*32+e*4+1]);
      pk.z = f2bf((xv[e*4+2]-mu)*rs*lntg[hf*32+e*4+2] + lntb[hf*32+e*4+2]);
      pk.w = f2bf((xv[e*4+3]-mu)*rs*lntg[hf*32+e*4+3] + lntb[hf*32+e*4+3]);
      *(ushort4*)(tA + r*LDSW + hf*32 + e*4) = pk;
    }
    if (t < 128) maskL[t] = mask[(size_t)(s0+t)*N_DIM + i];
  }
  __syncthreads();

  short8 af[4][2];
  #pragma unroll
  for (int x=0;x<4;++x)
    #pragma unroll
    for (int kk=0;kk<2;++kk)
      af[x][kk] = *(const short8*)(tA + (wr + x*16 + ln15)*LDSW + kk*32 + quad*8);

  floatx4 mAcc[4][2];
  #pragma unroll
  for (int x=0;x<4;++x){ mAcc[x][0]=(floatx4){0,0,0,0}; mAcc[x][1]=(floatx4){0,0,0,0}; }

  for (int hc=0; hc<4; ++hc){
    floatx4 h1A[4][2], h2A[4][2];
    #pragma unroll
    for (int x=0;x<4;++x){
      h1A[x][0]=(floatx4){0,0,0,0}; h1A[x][1]=(floatx4){0,0,0,0};
      h2A[x][0]=(floatx4){0,0,0,0}; h2A[x][1]=(floatx4){0,0,0,0};
    }
    short8 b1[2][2], b2[2][2];
    #pragma unroll
    for (int xj=0;xj<2;++xj)
      #pragma unroll
      for (int kk=0;kk<2;++kk){
        int hrow = hc*64 + wc2 + xj*16 + ln15;
        b1[xj][kk] = *(const short8*)(fc1b + hrow*CM + kk*32 + quad*8);
        b2[xj][kk] = *(const short8*)(fc2b + hrow*CM + kk*32 + quad*8);
      }
    #pragma unroll
    for (int kk=0;kk<2;++kk)
      #pragma unroll
      for (int x=0;x<4;++x)
        #pragma unroll
        for (int xj=0;xj<2;++xj){
          h1A[x][xj] = __builtin_amdgcn_mfma_f32_16x16x32_bf16(af[x][kk], b1[xj][kk], h1A[x][xj], 0,0,0);
          h2A[x][xj] = __builtin_amdgcn_mfma_f32_16x16x32_bf16(af[x][kk], b2[xj][kk], h2A[x][xj], 0,0,0);
        }
    __syncthreads();  // prev chunk's uC reads complete
    #pragma unroll
    for (int x=0;x<4;++x)
      #pragma unroll
      for (int xj=0;xj<2;++xj)
        #pragma unroll
        for (int r=0;r<4;++r){
          int s = wr + x*16 + quad*4 + r, c = wc2 + xj*16 + ln15;
          float hv = h1A[x][xj][r];
          float u = hv/(1.f+__expf(-hv)) * h2A[x][xj][r];
          uC[s*LDSW + c] = f2bf(u);
        }
    __syncthreads();
    short8 au[4][2], b3[2][2];
    #pragma unroll
    for (int x=0;x<4;++x)
      #pragma unroll
      for (int kk=0;kk<2;++kk)
        au[x][kk] = *(const short8*)(uC + (wr + x*16 + ln15)*LDSW + kk*32 + quad*8);
    #pragma unroll
    for (int xj=0;xj<2;++xj)
      #pragma unroll
      for (int kk=0;kk<2;++kk)
        b3[xj][kk] = *(const short8*)(fc3b + (wc2 + xj*16 + ln15)*HID + hc*64 + kk*32 + quad*8);
    #pragma unroll
    for (int kk=0;kk<2;++kk)
      #pragma unroll
      for (int x=0;x<4;++x)
        #pragma unroll
        for (int xj=0;xj<2;++xj)
          mAcc[x][xj] = __builtin_amdgcn_mfma_f32_16x16x32_bf16(au[x][kk], b3[xj][kk], mAcc[x][xj], 0,0,0);
  }
  __syncthreads();  // all uC/tA reads complete

  // m2 = m1 + mAcc -> global (fp32) + tA (bf16)
  #pragma unroll
  for (int x=0;x<4;++x)
    #pragma unroll
    for (int xj=0;xj<2;++xj)
      #pragma unroll
      for (int r=0;r<4;++r){
        int s = wr + x*16 + quad*4 + r, c = wc2 + xj*16 + ln15;
        size_t gi = (((size_t)(s0+s))*N_DIM + i)*CM + c;
        float m2v = m_io[gi] + mAcc[x][xj][r];
        m_io[gi] = m2v;
        tA[s*LDSW + c] = f2bf(m2v);
      }
  __syncthreads();

  { // LN2 from tA -> mo in uC
    int r = t>>1, hf = t&1;
    float xv[32];
    #pragma unroll
    for (int e=0;e<32;++e) xv[e] = bf2f(tA[r*LDSW + hf*32 + e]);
    float sm = 0.f;
    #pragma unroll
    for (int e=0;e<32;++e) sm += xv[e];
    sm += __shfl_xor(sm, 1, 64);
    float mu = sm * (1.0f/64.0f);
    float vr = 0.f;
    #pragma unroll
    for (int e=0;e<32;++e){ float d = xv[e]-mu; vr += d*d; }
    vr += __shfl_xor(vr, 1, 64);
    float rs = rsqrtf(vr*(1.0f/64.0f) + 1e-5f);
    #pragma unroll
    for (int e=0;e<8;++e){
      ushort4 pk;
      pk.x = f2bf((xv[e*4+0]-mu)*rs*lnog[hf*32+e*4+0] + lnob[hf*32+e*4+0]);
      pk.y = f2bf((xv[e*4+1]-mu)*rs*lnog[hf*32+e*4+1] + lnob[hf*32+e*4+1]);
      pk.z = f2bf((xv[e*4+2]-mu)*rs*lnog[hf*32+e*4+2] + lnob[hf*32+e*4+2]);
      pk.w = f2bf((xv[e*4+3]-mu)*rs*lnog[hf*32+e*4+3] + lnob[hf*32+e*4+3]);
      *(ushort4*)(uC + r*LDSW + hf*32 + e*4) = pk;
    }
  }
  __syncthreads();

  // GEMM3: mo @ [wa;wb]^T (K=64), masked transposed store
  floatx4 ab[4][2];
  #pragma unroll
  for (int x=0;x<4;++x){ ab[x][0]=(floatx4){0,0,0,0}; ab[x][1]=(floatx4){0,0,0,0}; }
  short8 am[4][2], bw[2][2];
  #pragma unroll
  for (int x=0;x<4;++x)
    #pragma unroll
    for (int kk=0;kk<2;++kk)
      am[x][kk] = *(const short8*)(uC + (wr + x*16 + ln15)*LDSW + kk*32 + quad*8);
  #pragma unroll
  for (int xj=0;xj<2;++xj)
    #pragma unroll
    for (int kk=0;kk<2;++kk)
      bw[xj][kk] = *(const short8*)(wabb + (wc2 + xj*16 + ln15)*CM + kk*32 + quad*8);
  #pragma unroll
  for (int kk=0;kk<2;++kk)
    #pragma unroll
    for (int x=0;x<4;++x)
      #pragma unroll
      for (int xj=0;xj<2;++xj)
        ab[x][xj] = __builtin_amdgcn_mfma_f32_16x16x32_bf16(am[x][kk], bw[xj][kk], ab[x][xj], 0,0,0);
  #pragma unroll
  for (int x=0;x<4;++x)
    #pragma unroll
    for (int xj=0;xj<2;++xj){
      int c = wc2 + xj*16 + ln15;
      int sbase = wr + x*16 + quad*4;
      ushort4 pk;
      #pragma unroll
      for (int r=0;r<4;++r) pk[r] = f2bf(ab[x][xj][r] * maskL[sbase+r]);
      unsigned short* dst = (c < 32)
        ? (a2g + ((size_t)i*COPM + c)*S_DIM + s0 + sbase)
        : (b2g + ((size_t)i*COPM + (c-32))*S_DIM + s0 + sbase);
      *(ushort4*)dst = pk;
    }
}

// ---------------- K8: 256x256-tile outer-product GEMM, BK=64, XOR-swizzled LDS ----------------
// BM=BN=256, BK=64, 512 thr = 8 waves (2M x 4N), wave tile 128x64.
// LDS 128KB: A bufs [2][256*64] then B bufs [2][256*64] (1 block/CU).
// Rows are 128B (8 x 16B slots) -> full 3-bit XOR swizzle slot^=row&7 makes
// fragment ds_read_b128 2-way bank-aliased (free). Double-buffered at K-tile
// granularity with counted vmcnt: stage kt+2 right after the barrier retiring
// kt's reads; vmcnt(8) guarantees kt+1 landed while kt+2's 8 loads stay in
// flight across the barrier. 64 MFMA between barriers; 2 barriers + 1 wait/kt.
__device__ __forceinline__ void k8_stage64(const unsigned short* Ag, const unsigned short* Bg,
                                           unsigned short* lds, int sel, int kt, int t){
  #pragma unroll
  for (int it=0; it<4; ++it){
    int ch = it*512 + t;                  // 2048 chunks of 16B per operand tile
    int row = ch>>3, sl = ch&7;
    int koff = (sl ^ (row&7))*8;          // inverse-swizzled global source
    size_t goff = (size_t)row*S_DIM + kt*64 + koff;
    gload16(Ag + goff, lds + sel*16384 + ch*8);
    gload16(Bg + goff, lds + 32768 + sel*16384 + ch*8);
  }
}

__global__ __launch_bounds__(512, 2) void k8_outer(
    const unsigned short* __restrict__ a2, const unsigned short* __restrict__ b2,
    const unsigned short* __restrict__ woutb, const float* __restrict__ num,
    const float* __restrict__ zin, const float* __restrict__ bout,
    float* __restrict__ zout)
{
  __shared__ unsigned short lds[65536];   // 128KB
  int t = threadIdx.x, lane = t&63, w = t>>6;
  int ln15 = lane&15, quad = lane>>4;
  int wm = w>>2, wn = w&3;
  int wr = wm*128, wcol = wn*64;
  int nb = blockIdx.x, mb = blockIdx.y;
  const unsigned short* Ag = a2 + (size_t)(mb*256)*S_DIM;
  const unsigned short* Bg = b2 + (size_t)(nb*256)*S_DIM;

  floatx4 acc[8][4];
  #pragma unroll
  for (int rf=0; rf<8; ++rf)
    #pragma unroll
    for (int cf=0; cf<4; ++cf) acc[rf][cf] = (floatx4){0.f,0.f,0.f,0.f};

  k8_stage64(Ag, Bg, lds, 0, 0, t);
  k8_stage64(Ag, Bg, lds, 1, 1, t);
  vmwait8();            // tile 0 landed (tile 1's 8 loads remain in flight)
  barrier_nodrain();

  for (int kt=0; kt<16; ++kt){
    const unsigned short* Ab = lds + (kt&1)*16384;
    const unsigned short* Bb = lds + 32768 + (kt&1)*16384;
    #pragma unroll
    for (int kk=0; kk<2; ++kk){
      int sw = (((kk<<2) | quad) ^ (ln15 & 7)) << 3;   // swizzled 16B slot (ushorts)
      short8 af[8], bf4[4];
      #pragma unroll
      for (int rf=0; rf<8; ++rf)
        af[rf] = *(const short8*)(Ab + ((wr + rf*16 + ln15)<<6) + sw);
      #pragma unroll
      for (int cf=0; cf<4; ++cf)
        bf4[cf] = *(const short8*)(Bb + ((wcol + cf*16 + ln15)<<6) + sw);
      __builtin_amdgcn_s_setprio(1);
      #pragma unroll
      for (int rf=0; rf<8; ++rf)
        #pragma unroll
        for (int cf=0; cf<4; ++cf)
          acc[rf][cf] = __builtin_amdgcn_mfma_f32_16x16x32_bf16(af[rf], bf4[cf], acc[rf][cf], 0, 0, 0);
      __builtin_amdgcn_s_setprio(0);
    }
    barrier_nodrain();                          // all reads of buf (kt&1) retired
    if (kt < 14) k8_stage64(Ag, Bg, lds, kt&1, kt+2, t);
    if (kt <= 13) vmwait8();                    // tile kt+1 landed; kt+2 stays in flight
    else if (kt == 14) vmwait0();               // drain tail: tile 15 landed
    barrier_nodrain();                          // collective: next tile ready for all waves
  }

  // ---- fused epilogue: z[i,j,:] += P(i,j,:,:) @ wout^T / num + bout ----
  // P = 256x256 bf16 C-tile, staged into LDS as two 128x256 halves (ih).
  unsigned short* P = lds;                      // [128][256]
  #pragma unroll
  for (int ih=0; ih<2; ++ih){
    if (wm == ih){
      #pragma unroll
      for (int rf=0; rf<8; ++rf)
        #pragma unroll
        for (int cf=0; cf<4; ++cf)
          #pragma unroll
          for (int r=0; r<4; ++r)
            P[(rf*16 + quad*4 + r)*256 + wcol + cf*16 + ln15] = f2bf(acc[rf][cf][r]);
    }
    barrier_nodrain();
    // pairs this pass: p = i_ll*8 + j_ll, i_ll in [0,4) (global i = mb*8+ih*4+i_ll), j_ll in [0,8)
    int prow0 = (ln15>>3)*32;                   // i_ll 0..1 (rf2=0)
    int prow1 = prow0 + 64;                     // i_ll 2..3 (rf2=1)
    int pcol  = (ln15&7)*32 + quad*8;
    const unsigned short* wrow = woutb + (size_t)(w*16 + ln15)*1024 + quad*8;
    floatx4 e0 = (floatx4){0.f,0.f,0.f,0.f};
    floatx4 e1 = (floatx4){0.f,0.f,0.f,0.f};
    #pragma unroll 8
    for (int ks=0; ks<32; ++ks){
      short8 wf  = *(const short8*)(wrow + ks*32);
      short8 pa0 = *(const short8*)(P + (prow0 + ks)*256 + pcol);
      short8 pa1 = *(const short8*)(P + (prow1 + ks)*256 + pcol);
      e0 = __builtin_amdgcn_mfma_f32_16x16x32_bf16(pa0, wf, e0, 0, 0, 0);
      e1 = __builtin_amdgcn_mfma_f32_16x16x32_bf16(pa1, wf, e1, 0, 0, 0);
    }
    #pragma unroll
    for (int rf2=0; rf2<2; ++rf2){
      #pragma unroll
      for (int r=0; r<4; ++r){
        int p = rf2*16 + quad*4 + r;
        int i = mb*8 + ih*4 + (p>>3), j = nb*8 + (p&7);
        float nv = num[(size_t)i*N_DIM + j];
        size_t zi = ((size_t)i*N_DIM + j)*CZ + w*16 + ln15;
        float av = (rf2==0) ? e0[r] : e1[r];
        zout[zi] = zin[zi] + av*(1.0f/nv) + bout[w*16 + ln15];
      }
    }
    barrier_nodrain();                          // P reads done before next pass overwrites
  }
}

extern "C" void kernel_launch(void* const* d_in, const int* in_sizes, int n_in,
                              void* d_out, int out_size, void* d_ws, size_t ws_size,
                              hipStream_t stream)
{
  const float* z    = (const float*)d_in[0];
  const float* m    = (const float*)d_in[1];
  const float* tm   = (const float*)d_in[2];
  const float* mask = (const float*)d_in[3];
  const float* lnzg = (const float*)d_in[4];
  const float* lnzb = (const float*)d_in[5];
  const float* wz   = (const float*)d_in[6];
  const float* lnmg = (const float*)d_in[7];
  const float* lnmb = (const float*)d_in[8];
  const float* wm   = (const float*)d_in[9];
  const float* wg   = (const float*)d_in[10];
  const float* wo   = (const float*)d_in[11];
  const float* lntg = (const float*)d_in[12];
  const float* lntb = (const float*)d_in[13];
  const float* fc1  = (const float*)d_in[14];
  const float* fc2  = (const float*)d_in[15];
  const float* fc3  = (const float*)d_in[16];
  const float* lnog = (const float*)d_in[17];
  const float* lnob = (const float*)d_in[18];
  const float* wa   = (const float*)d_in[19];
  const float* wb   = (const float*)d_in[20];
  const float* wout = (const float*)d_in[21];
  const float* bout = (const float*)d_in[22];

  float* zout = (float*)d_out;
  float* mout = zout + (size_t)N_DIM*N_DIM*CZ;

  // z-region of d_out doubles as scratch for buffers dead before k8 writes z:
  char* zs = (char*)d_out;
  unsigned short* mn     = (unsigned short*)zs;               // 50,331,648 B
  float*          logits = (float*)(zs + 50331648);           //  4,718,592 B
  unsigned short* watt   = (unsigned short*)(zs + 55050240);  //  2,359,296 B
  unsigned short* W      = (unsigned short*)(zs + 57409536);  // bf16 weights (dead before k8)
  unsigned short* wgb  = W;          // 16384
  unsigned short* wob  = W + 16384;  // 16384
  unsigned short* fc1b = W + 32768;  // 16384
  unsigned short* fc2b = W + 49152;  // 16384
  unsigned short* fc3b = W + 65536;  // 16384
  unsigned short* wabb = W + 81920;  //  4096

  char* ws = (char*)d_ws;
  unsigned short* v2    = (unsigned short*)ws;                // 201,326,592 B
  unsigned short* o2    = (unsigned short*)(ws + 201326592);  // 201,326,592 B
  float*          num   = (float*)(ws + 402653184);           //     589,824 B
  unsigned short* woutb = (unsigned short*)(ws + 403243008);  //     262,144 B
  unsigned short* a2 = v2;                                    // alias: v2 dead after k4
  unsigned short* b2 = v2 + (size_t)MO*S_DIM;

  kcvt<<<64, 256, 0, stream>>>(wg,  wgb,  16384);
  kcvt<<<64, 256, 0, stream>>>(wo,  wob,  16384);
  kcvt<<<64, 256, 0, stream>>>(fc1, fc1b, 16384);
  kcvt<<<64, 256, 0, stream>>>(fc2, fc2b, 16384);
  kcvt<<<64, 256, 0, stream>>>(fc3, fc3b, 16384);
  kcvt<<<8,  256, 0, stream>>>(wa,  wabb, 2048);
  kcvt<<<8,  256, 0, stream>>>(wb,  wabb+2048, 2048);
  kcvt<<<512,256, 0, stream>>>(wout, woutb, 131072);

  k1_logits  <<<36864, 256, 0, stream>>>(z, tm, lnzg, lnzb, wz, logits);
  k2_softmax <<<768, 256, 0, stream>>>(logits, watt);
  k3_lnm_v   <<<dim3(24,1024), 256, 0, stream>>>(m, lnmg, lnmb, wm, mn, v2);
  k7_num     <<<dim3(24,24), 256, 0, stream>>>(mask, num);
  k4_attn    <<<dim3(256,3,8), 256, 0, stream>>>(watt, v2, o2);
  k5m        <<<dim3(8,384), 256, 0, stream>>>(m, mn, o2, wgb, wob, mout);
  k6m        <<<dim3(8,384), 256, 0, stream>>>(mout, mask, lntg, lntb, fc1b, fc2b, fc3b,
                                               lnog, lnob, wabb, a2, b2);
  k8_outer   <<<dim3(48,48), 512, 0, stream>>>(a2, b2, woutb, num, z, bout, zout);
}

// Round 4
// 1772.266 us; speedup vs baseline: 1.1502x; 1.0018x over previous
//
#include <hip/hip_runtime.h>

#define S_DIM 1024
#define N_DIM 384
#define CZ    128
#define CM    64
#define H_DIM 8
#define CH    32
#define COPM  32
#define HID   256
#define SD    32768   // S_DIM*CH
#define MO    12288   // N_DIM*COPM
#define LDSW  72      // padded LDS row stride (ushorts), 144B = 16B-aligned

typedef __attribute__((ext_vector_type(8))) short  short8;
typedef __attribute__((ext_vector_type(4))) float  floatx4;

__device__ __forceinline__ float bf2f(unsigned short u){
  union { unsigned int u; float f; } v; v.u = ((unsigned int)u)<<16; return v.f;
}
__device__ __forceinline__ unsigned short f2bf(float f){
  union { float f; unsigned int u; } v; v.f = f;
  return (unsigned short)((v.u + 0x7fffu + ((v.u>>16)&1u)) >> 16);
}
__device__ __forceinline__ float red64(float x){
  #pragma unroll
  for (int off=1; off<64; off<<=1) x += __shfl_xor(x, off, 64);
  return x;
}
__device__ __forceinline__ float red16(float x){
  #pragma unroll
  for (int off=1; off<16; off<<=1) x += __shfl_xor(x, off, 64);
  return x;
}
__device__ __forceinline__ void gload16(const void* g, void* l){
  __builtin_amdgcn_global_load_lds((__attribute__((address_space(1))) void*)(g),
                                   (__attribute__((address_space(3))) void*)(l), 16, 0, 0);
}
// raw barrier + compiler memory fence (does NOT auto-drain vmcnt like __syncthreads)
__device__ __forceinline__ void barrier_nodrain(){
  asm volatile("" ::: "memory");
  __builtin_amdgcn_s_barrier();
  asm volatile("" ::: "memory");
}
__device__ __forceinline__ void vmwait0(){ asm volatile("s_waitcnt vmcnt(0)" ::: "memory"); }
__device__ __forceinline__ void lgkmwait0(){ asm volatile("s_waitcnt lgkmcnt(0)" ::: "memory"); }
__device__ __forceinline__ void lgkmwait8(){ asm volatile("s_waitcnt lgkmcnt(8)" ::: "memory"); }

// ---------------- generic fp32 -> bf16 convert ----------------
__global__ void kcvt(const float* __restrict__ w, unsigned short* __restrict__ o, int n){
  int i = blockIdx.x*256 + threadIdx.x;
  if (i < n) o[i] = f2bf(w[i]);
}

// ---------------- K1: logits[h][i][j] = LN(z)@wz^T + mask ----------------
__global__ __launch_bounds__(256) void k1_logits(
    const float* __restrict__ z, const float* __restrict__ tm,
    const float* __restrict__ g, const float* __restrict__ b,
    const float* __restrict__ wz, float* __restrict__ logits)
{
  int idx  = blockIdx.x*4 + (threadIdx.x>>6);      // (i,j) flat, 147456
  int lane = threadIdx.x & 63;
  const float* zp = z + (size_t)idx*CZ;
  float x0 = zp[lane], x1 = zp[lane+64];
  float mu = red64(x0+x1) * (1.0f/128.0f);
  float d0 = x0-mu, d1 = x1-mu;
  float var = red64(d0*d0 + d1*d1) * (1.0f/128.0f);
  float rs = rsqrtf(var + 1e-5f);
  float y0 = d0*rs*g[lane]    + b[lane];
  float y1 = d1*rs*g[lane+64] + b[lane+64];
  float mterm = (1.0f - tm[idx]) * (-1e6f);
  #pragma unroll
  for (int h=0; h<H_DIM; ++h){
    float p = y0*wz[h*CZ+lane] + y1*wz[h*CZ+64+lane];
    p = red64(p);
    if (lane==0) logits[(size_t)h*N_DIM*N_DIM + idx] = p + mterm;
  }
}

// ---------------- K2: softmax rows -> w_att bf16 ----------------
__global__ __launch_bounds__(256) void k2_softmax(
    const float* __restrict__ logits, unsigned short* __restrict__ watt)
{
  int row  = blockIdx.x*4 + (threadIdx.x>>6);      // 3072 rows (h*384+i)
  int lane = threadIdx.x & 63;
  const float* p = logits + (size_t)row*N_DIM;
  float v[6]; float mx = -3.4e38f;
  #pragma unroll
  for (int e=0;e<6;++e){ v[e] = p[lane + e*64]; mx = fmaxf(mx, v[e]); }
  #pragma unroll
  for (int off=1; off<64; off<<=1) mx = fmaxf(mx, __shfl_xor(mx, off, 64));
  float sum = 0.f;
  #pragma unroll
  for (int e=0;e<6;++e){ v[e] = __expf(v[e]-mx); sum += v[e]; }
  sum = red64(sum);
  float inv = 1.0f/sum;
  #pragma unroll
  for (int e=0;e<6;++e) watt[(size_t)row*N_DIM + lane + e*64] = f2bf(v[e]*inv);
}

// ---------------- K3: mn = LN(m) (bf16), v2[h][(s,d)][j] = mn@wm^T ----------------
__global__ __launch_bounds__(256) void k3_lnm_v(
    const float* __restrict__ m, const float* __restrict__ g, const float* __restrict__ b,
    const float* __restrict__ wm, unsigned short* __restrict__ mn, unsigned short* __restrict__ v2)
{
  __shared__ float mnL[16*64];
  int s = blockIdx.y, j0 = blockIdx.x*16, t = threadIdx.x;
  {
    int r = t>>4, q = t&15;
    size_t row = (size_t)s*N_DIM + j0 + r;
    float4 x = *(const float4*)(m + row*CM + q*4);
    float mu = red16(x.x+x.y+x.z+x.w) * (1.0f/64.0f);
    float4 d = {x.x-mu, x.y-mu, x.z-mu, x.w-mu};
    float var = red16(d.x*d.x+d.y*d.y+d.z*d.z+d.w*d.w) * (1.0f/64.0f);
    float rs = rsqrtf(var + 1e-5f);
    float4 y;
    y.x = d.x*rs*g[q*4+0] + b[q*4+0];
    y.y = d.y*rs*g[q*4+1] + b[q*4+1];
    y.z = d.z*rs*g[q*4+2] + b[q*4+2];
    y.w = d.w*rs*g[q*4+3] + b[q*4+3];
    mnL[r*64+q*4+0]=y.x; mnL[r*64+q*4+1]=y.y; mnL[r*64+q*4+2]=y.z; mnL[r*64+q*4+3]=y.w;
    ushort4 u4 = {f2bf(y.x), f2bf(y.y), f2bf(y.z), f2bf(y.w)};
    *(ushort4*)(mn + row*CM + q*4) = u4;
  }
  __syncthreads();
  float acc[16];
  #pragma unroll
  for (int r=0;r<16;++r) acc[r]=0.f;
  const float4* wm4  = (const float4*)wm;
  const float4* mnL4 = (const float4*)mnL;
  #pragma unroll 4
  for (int c4=0;c4<16;++c4){
    float4 w = wm4[t*16 + c4];
    #pragma unroll
    for (int r=0;r<16;++r){
      float4 x = mnL4[r*16 + c4];
      acc[r] += x.x*w.x + x.y*w.y + x.z*w.z + x.w*w.w;
    }
  }
  int h = t>>5, d2 = t&31;
  short8 p0, p1;
  #pragma unroll
  for (int e=0;e<8;++e){ p0[e] = (short)f2bf(acc[e]); p1[e] = (short)f2bf(acc[8+e]); }
  unsigned short* dst = v2 + ((size_t)h*SD + (size_t)s*CH + d2)*N_DIM + j0;
  *(short8*)dst       = p0;
  *(short8*)(dst + 8) = p1;
}

// ---------------- K7: num[i][j] = max(1, sum_s mask[s,i]*mask[s,j]) ----------------
__global__ __launch_bounds__(256) void k7_num(
    const float* __restrict__ mask, float* __restrict__ num)
{
  __shared__ float mA[64*16], mB[64*16];
  int i0 = blockIdx.y*16, j0 = blockIdx.x*16, t = threadIdx.x;
  int ti = t>>4, tj = t&15;
  float acc = 0.f;
  for (int s0=0; s0<S_DIM; s0+=64){
    #pragma unroll
    for (int k=0;k<4;++k){
      int idx = t + k*256; int ss = idx>>4, c = idx&15;
      mA[idx] = mask[(size_t)(s0+ss)*N_DIM + i0 + c];
      mB[idx] = mask[(size_t)(s0+ss)*N_DIM + j0 + c];
    }
    __syncthreads();
    #pragma unroll 8
    for (int ss=0; ss<64; ++ss) acc += mA[ss*16+ti] * mB[ss*16+tj];
    __syncthreads();
  }
  num[(size_t)(i0+ti)*N_DIM + j0+tj] = fmaxf(acc, 1.0f);
}

// ---------------- shared 128x128 A*B^T core (m97 pattern, XOR-swizzled LDS) ----------------
// (still used by k4_attn)
__device__ __forceinline__ void gemm_bt_core(
    const unsigned short* __restrict__ A, const unsigned short* __restrict__ B,
    int lda, int ldb, int K,
    unsigned short* As, unsigned short* Bs, floatx4 acc[4][4],
    int wr, int wc, int ln15, int quad)
{
  int t = threadIdx.x;
  for (int k0=0; k0<K; k0+=64){
    #pragma unroll
    for (int it=0; it<4; ++it){
      int ch = it*256 + t;                  // 1024 chunks of 16B per operand
      int row = ch>>3, slot = ch&7;
      int koff = (slot ^ (row&7))*8;        // inverse-swizzled global source
      gload16(A + (size_t)row*lda + k0 + koff, As + ch*8);
      gload16(B + (size_t)row*ldb + k0 + koff, Bs + ch*8);
    }
    __syncthreads();
    #pragma unroll
    for (int kk=0; kk<2; ++kk){
      int sw = (((kk<<2) | quad) ^ (ln15 & 7)) << 3;   // swizzled 16B slot (ushorts)
      short8 af[4], bfr[4];
      #pragma unroll
      for (int x=0;x<4;++x) af[x]  = *(const short8*)(As + ((wr + x*16 + ln15)<<6) + sw);
      #pragma unroll
      for (int x=0;x<4;++x) bfr[x] = *(const short8*)(Bs + ((wc + x*16 + ln15)<<6) + sw);
      #pragma unroll
      for (int ti=0;ti<4;++ti)
        #pragma unroll
        for (int tj=0;tj<4;++tj)
          acc[ti][tj] = __builtin_amdgcn_mfma_f32_16x16x32_bf16(af[ti], bfr[tj], acc[ti][tj], 0, 0, 0);
    }
    __syncthreads();
  }
}

// ---------------- K4: per-head attention o2[h][i][(s,d)] = att @ v2^T ----------------
__global__ __launch_bounds__(256) void k4_attn(
    const unsigned short* __restrict__ watt, const unsigned short* __restrict__ v2,
    unsigned short* __restrict__ o2)
{
  __shared__ unsigned short smem[16384];
  int t = threadIdx.x, lane = t&63, w = t>>6;
  int ln15 = lane&15, quad = lane>>4;
  int wr = (w>>1)*64, wc = (w&1)*64;
  int nb = blockIdx.x, mb = blockIdx.y, h = blockIdx.z;
  const unsigned short* A = watt + (size_t)h*N_DIM*N_DIM + (size_t)(mb*128)*N_DIM;
  const unsigned short* B = v2 + ((size_t)h*SD + (size_t)nb*128)*N_DIM;
  floatx4 acc[4][4];
  #pragma unroll
  for (int ti=0;ti<4;++ti)
    #pragma unroll
    for (int tj=0;tj<4;++tj) acc[ti][tj] = (floatx4){0.f,0.f,0.f,0.f};
  gemm_bt_core(A, B, N_DIM, N_DIM, N_DIM, smem, smem+8192, acc, wr, wc, ln15, quad);
  unsigned short* C = o2 + ((size_t)h*N_DIM + mb*128)*SD + nb*128;
  #pragma unroll
  for (int ti=0;ti<4;++ti)
    #pragma unroll
    for (int tj=0;tj<4;++tj)
      #pragma unroll
      for (int r=0;r<4;++r)
        C[(size_t)(wr+ti*16+quad*4+r)*SD + wc + tj*16 + ln15] = f2bf(acc[ti][tj][r]);
}

// ---------------- K5m: MFMA PWA update: m1 = m + (sigmoid(mn@wg^T) * o) @ wo^T ----------------
__global__ __launch_bounds__(256) void k5m(
    const float* __restrict__ m_in, const unsigned short* __restrict__ mn,
    const unsigned short* __restrict__ o2,
    const unsigned short* __restrict__ wgb, const unsigned short* __restrict__ wob,
    float* __restrict__ m1_out)
{
  __shared__ unsigned short tA[128*LDSW];
  __shared__ unsigned short uC[128*LDSW];
  int i = blockIdx.y, s0 = blockIdx.x*128, t = threadIdx.x;
  int lane = t&63, w = t>>6, ln15 = lane&15, quad = lane>>4;
  int wr = (w>>1)*64, wc2 = (w&1)*32;

  { // stage mn rows (s0+r, i) -> tA
    int r = t>>1, hf = t&1;
    const unsigned short* src = mn + (((size_t)(s0+r))*N_DIM + i)*CM + hf*32;
    #pragma unroll
    for (int e=0;e<4;++e)
      *(short8*)(tA + r*LDSW + hf*32 + e*8) = *(const short8*)(src + e*8);
  }
  __syncthreads();

  short8 af[4][2];
  #pragma unroll
  for (int x=0;x<4;++x)
    #pragma unroll
    for (int kk=0;kk<2;++kk)
      af[x][kk] = *(const short8*)(tA + (wr + x*16 + ln15)*LDSW + kk*32 + quad*8);

  floatx4 mAcc[4][2];
  #pragma unroll
  for (int x=0;x<4;++x){ mAcc[x][0]=(floatx4){0,0,0,0}; mAcc[x][1]=(floatx4){0,0,0,0}; }

  for (int hc=0; hc<4; ++hc){
    floatx4 gA[4][2];
    #pragma unroll
    for (int x=0;x<4;++x){ gA[x][0]=(floatx4){0,0,0,0}; gA[x][1]=(floatx4){0,0,0,0}; }
    short8 bg[2][2];
    #pragma unroll
    for (int xj=0;xj<2;++xj)
      #pragma unroll
      for (int kk=0;kk<2;++kk)
        bg[xj][kk] = *(const short8*)(wgb + (hc*64 + wc2 + xj*16 + ln15)*CM + kk*32 + quad*8);
    #pragma unroll
    for (int kk=0;kk<2;++kk)
      #pragma unroll
      for (int x=0;x<4;++x)
        #pragma unroll
        for (int xj=0;xj<2;++xj)
          gA[x][xj] = __builtin_amdgcn_mfma_f32_16x16x32_bf16(af[x][kk], bg[xj][kk], gA[x][xj], 0,0,0);
    __syncthreads();  // prev chunk's uC reads complete
    #pragma unroll
    for (int x=0;x<4;++x)
      #pragma unroll
      for (int xj=0;xj<2;++xj)
        #pragma unroll
        for (int r=0;r<4;++r){
          int s = wr + x*16 + quad*4 + r, c = wc2 + xj*16 + ln15;
          int hd = hc*64 + c, h = hd>>5, d = hd&31;
          float gv = 1.f/(1.f+__expf(-gA[x][xj][r]));
          float ov = bf2f(o2[((size_t)(h*N_DIM + i))*SD + (size_t)(s0+s)*CH + d]);
          uC[s*LDSW + c] = f2bf(gv*ov);
        }
    __syncthreads();
    short8 au[4][2], bo[2][2];
    #pragma unroll
    for (int x=0;x<4;++x)
      #pragma unroll
      for (int kk=0;kk<2;++kk)
        au[x][kk] = *(const short8*)(uC + (wr + x*16 + ln15)*LDSW + kk*32 + quad*8);
    #pragma unroll
    for (int xj=0;xj<2;++xj)
      #pragma unroll
      for (int kk=0;kk<2;++kk)
        bo[xj][kk] = *(const short8*)(wob + (wc2 + xj*16 + ln15)*HID + hc*64 + kk*32 + quad*8);
    #pragma unroll
    for (int kk=0;kk<2;++kk)
      #pragma unroll
      for (int x=0;x<4;++x)
        #pragma unroll
        for (int xj=0;xj<2;++xj)
          mAcc[x][xj] = __builtin_amdgcn_mfma_f32_16x16x32_bf16(au[x][kk], bo[xj][kk], mAcc[x][xj], 0,0,0);
  }
  #pragma unroll
  for (int x=0;x<4;++x)
    #pragma unroll
    for (int xj=0;xj<2;++xj)
      #pragma unroll
      for (int r=0;r<4;++r){
        int s = wr + x*16 + quad*4 + r, c = wc2 + xj*16 + ln15;
        size_t gi = (((size_t)(s0+s))*N_DIM + i)*CM + c;
        m1_out[gi] = m_in[gi] + mAcc[x][xj][r];
      }
}

// ---------------- K6m: MFMA SwiGLU transition + LN + a/b projections ----------------
__global__ __launch_bounds__(256) void k6m(
    float* __restrict__ m_io, const float* __restrict__ mask,
    const float* __restrict__ lntg, const float* __restrict__ lntb,
    const unsigned short* __restrict__ fc1b, const unsigned short* __restrict__ fc2b,
    const unsigned short* __restrict__ fc3b,
    const float* __restrict__ lnog, const float* __restrict__ lnob,
    const unsigned short* __restrict__ wabb,
    unsigned short* __restrict__ a2g, unsigned short* __restrict__ b2g)
{
  __shared__ unsigned short tA[128*LDSW];
  __shared__ unsigned short uC[128*LDSW];
  __shared__ float maskL[128];
  int i = blockIdx.y, s0 = blockIdx.x*128, t = threadIdx.x;
  int lane = t&63, w = t>>6, ln15 = lane&15, quad = lane>>4;
  int wr = (w>>1)*64, wc2 = (w&1)*32;

  { // LN1 of m1 rows -> tA (bf16)
    int r = t>>1, hf = t&1;
    const float4* src = (const float4*)(m_io + (((size_t)(s0+r))*N_DIM + i)*CM + hf*32);
    float xv[32];
    #pragma unroll
    for (int e=0;e<8;++e){
      float4 x = src[e];
      xv[e*4+0]=x.x; xv[e*4+1]=x.y; xv[e*4+2]=x.z; xv[e*4+3]=x.w;
    }
    float sm = 0.f;
    #pragma unroll
    for (int e=0;e<32;++e) sm += xv[e];
    sm += __shfl_xor(sm, 1, 64);
    float mu = sm * (1.0f/64.0f);
    float vr = 0.f;
    #pragma unroll
    for (int e=0;e<32;++e){ float d = xv[e]-mu; vr += d*d; }
    vr += __shfl_xor(vr, 1, 64);
    float rs = rsqrtf(vr*(1.0f/64.0f) + 1e-5f);
    #pragma unroll
    for (int e=0;e<8;++e){
      ushort4 pk;
      pk.x = f2bf((xv[e*4+0]-mu)*rs*lntg[hf*32+e*4+0] + lntb[hf*32+e*4+0]);
      pk.y = f2bf((xv[e*4+1]-mu)*rs*lntg[hf*32+e*4+1] + lntb[hf*32+e*4+1]);
      pk.z = f2bf((xv[e*4+2]-mu)*rs*lntg[hf*32+e*4+2] + lntb[hf*32+e*4+2]);
      pk.w = f2bf((xv[e*4+3]-mu)*rs*lntg[hf*32+e*4+3] + lntb[hf*32+e*4+3]);
      *(ushort4*)(tA + r*LDSW + hf*32 + e*4) = pk;
    }
    if (t < 128) maskL[t] = mask[(size_t)(s0+t)*N_DIM + i];
  }
  __syncthreads();

  short8 af[4][2];
  #pragma unroll
  for (int x=0;x<4;++x)
    #pragma unroll
    for (int kk=0;kk<2;++kk)
      af[x][kk] = *(const short8*)(tA + (wr + x*16 + ln15)*LDSW + kk*32 + quad*8);

  floatx4 mAcc[4][2];
  #pragma unroll
  for (int x=0;x<4;++x){ mAcc[x][0]=(floatx4){0,0,0,0}; mAcc[x][1]=(floatx4){0,0,0,0}; }

  for (int hc=0; hc<4; ++hc){
    floatx4 h1A[4][2], h2A[4][2];
    #pragma unroll
    for (int x=0;x<4;++x){
      h1A[x][0]=(floatx4){0,0,0,0}; h1A[x][1]=(floatx4){0,0,0,0};
      h2A[x][0]=(floatx4){0,0,0,0}; h2A[x][1]=(floatx4){0,0,0,0};
    }
    short8 b1[2][2], b2[2][2];
    #pragma unroll
    for (int xj=0;xj<2;++xj)
      #pragma unroll
      for (int kk=0;kk<2;++kk){
        int hrow = hc*64 + wc2 + xj*16 + ln15;
        b1[xj][kk] = *(const short8*)(fc1b + hrow*CM + kk*32 + quad*8);
        b2[xj][kk] = *(const short8*)(fc2b + hrow*CM + kk*32 + quad*8);
      }
    #pragma unroll
    for (int kk=0;kk<2;++kk)
      #pragma unroll
      for (int x=0;x<4;++x)
        #pragma unroll
        for (int xj=0;xj<2;++xj){
          h1A[x][xj] = __builtin_amdgcn_mfma_f32_16x16x32_bf16(af[x][kk], b1[xj][kk], h1A[x][xj], 0,0,0);
          h2A[x][xj] = __builtin_amdgcn_mfma_f32_16x16x32_bf16(af[x][kk], b2[xj][kk], h2A[x][xj], 0,0,0);
        }
    __syncthreads();  // prev chunk's uC reads complete
    #pragma unroll
    for (int x=0;x<4;++x)
      #pragma unroll
      for (int xj=0;xj<2;++xj)
        #pragma unroll
        for (int r=0;r<4;++r){
          int s = wr + x*16 + quad*4 + r, c = wc2 + xj*16 + ln15;
          float hv = h1A[x][xj][r];
          float u = hv/(1.f+__expf(-hv)) * h2A[x][xj][r];
          uC[s*LDSW + c] = f2bf(u);
        }
    __syncthreads();
    short8 au[4][2], b3[2][2];
    #pragma unroll
    for (int x=0;x<4;++x)
      #pragma unroll
      for (int kk=0;kk<2;++kk)
        au[x][kk] = *(const short8*)(uC + (wr + x*16 + ln15)*LDSW + kk*32 + quad*8);
    #pragma unroll
    for (int xj=0;xj<2;++xj)
      #pragma unroll
      for (int kk=0;kk<2;++kk)
        b3[xj][kk] = *(const short8*)(fc3b + (wc2 + xj*16 + ln15)*HID + hc*64 + kk*32 + quad*8);
    #pragma unroll
    for (int kk=0;kk<2;++kk)
      #pragma unroll
      for (int x=0;x<4;++x)
        #pragma unroll
        for (int xj=0;xj<2;++xj)
          mAcc[x][xj] = __builtin_amdgcn_mfma_f32_16x16x32_bf16(au[x][kk], b3[xj][kk], mAcc[x][xj], 0,0,0);
  }
  __syncthreads();  // all uC/tA reads complete

  // m2 = m1 + mAcc -> global (fp32) + tA (bf16)
  #pragma unroll
  for (int x=0;x<4;++x)
    #pragma unroll
    for (int xj=0;xj<2;++xj)
      #pragma unroll
      for (int r=0;r<4;++r){
        int s = wr + x*16 + quad*4 + r, c = wc2 + xj*16 + ln15;
        size_t gi = (((size_t)(s0+s))*N_DIM + i)*CM + c;
        float m2v = m_io[gi] + mAcc[x][xj][r];
        m_io[gi] = m2v;
        tA[s*LDSW + c] = f2bf(m2v);
      }
  __syncthreads();

  { // LN2 from tA -> mo in uC
    int r = t>>1, hf = t&1;
    float xv[32];
    #pragma unroll
    for (int e=0;e<32;++e) xv[e] = bf2f(tA[r*LDSW + hf*32 + e]);
    float sm = 0.f;
    #pragma unroll
    for (int e=0;e<32;++e) sm += xv[e];
    sm += __shfl_xor(sm, 1, 64);
    float mu = sm * (1.0f/64.0f);
    float vr = 0.f;
    #pragma unroll
    for (int e=0;e<32;++e){ float d = xv[e]-mu; vr += d*d; }
    vr += __shfl_xor(vr, 1, 64);
    float rs = rsqrtf(vr*(1.0f/64.0f) + 1e-5f);
    #pragma unroll
    for (int e=0;e<8;++e){
      ushort4 pk;
      pk.x = f2bf((xv[e*4+0]-mu)*rs*lnog[hf*32+e*4+0] + lnob[hf*32+e*4+0]);
      pk.y = f2bf((xv[e*4+1]-mu)*rs*lnog[hf*32+e*4+1] + lnob[hf*32+e*4+1]);
      pk.z = f2bf((xv[e*4+2]-mu)*rs*lnog[hf*32+e*4+2] + lnob[hf*32+e*4+2]);
      pk.w = f2bf((xv[e*4+3]-mu)*rs*lnog[hf*32+e*4+3] + lnob[hf*32+e*4+3]);
      *(ushort4*)(uC + r*LDSW + hf*32 + e*4) = pk;
    }
  }
  __syncthreads();

  // GEMM3: mo @ [wa;wb]^T (K=64), masked transposed store
  floatx4 ab[4][2];
  #pragma unroll
  for (int x=0;x<4;++x){ ab[x][0]=(floatx4){0,0,0,0}; ab[x][1]=(floatx4){0,0,0,0}; }
  short8 am[4][2], bw[2][2];
  #pragma unroll
  for (int x=0;x<4;++x)
    #pragma unroll
    for (int kk=0;kk<2;++kk)
      am[x][kk] = *(const short8*)(uC + (wr + x*16 + ln15)*LDSW + kk*32 + quad*8);
  #pragma unroll
  for (int xj=0;xj<2;++xj)
    #pragma unroll
    for (int kk=0;kk<2;++kk)
      bw[xj][kk] = *(const short8*)(wabb + (wc2 + xj*16 + ln15)*CM + kk*32 + quad*8);
  #pragma unroll
  for (int kk=0;kk<2;++kk)
    #pragma unroll
    for (int x=0;x<4;++x)
      #pragma unroll
      for (int xj=0;xj<2;++xj)
        ab[x][xj] = __builtin_amdgcn_mfma_f32_16x16x32_bf16(am[x][kk], bw[xj][kk], ab[x][xj], 0,0,0);
  #pragma unroll
  for (int x=0;x<4;++x)
    #pragma unroll
    for (int xj=0;xj<2;++xj){
      int c = wc2 + xj*16 + ln15;
      int sbase = wr + x*16 + quad*4;
      ushort4 pk;
      #pragma unroll
      for (int r=0;r<4;++r) pk[r] = f2bf(ab[x][xj][r] * maskL[sbase+r]);
      unsigned short* dst = (c < 32)
        ? (a2g + ((size_t)i*COPM + c)*S_DIM + s0 + sbase)
        : (b2g + ((size_t)i*COPM + (c-32))*S_DIM + s0 + sbase);
      *(ushort4*)dst = pk;
    }
}

// ---------------- K8: 256x256 outer-product GEMM, m201-style 8-phase schedule ----------------
// BM=BN=256, BK=64, 512 thr = 8 waves (2M x 4N), wave tile 128x64.
// LDS 128KB: A[2 dbuf][256x64] | B[2 dbuf][256x64], XOR-swizzled slots.
// Per K-tile, 4 phases, each {ds_read subtile || stage half-tile -> barrier ->
// lgkmcnt(0) -> setprio(1) 16 MFMA setprio(0) -> barrier}. vmcnt(0) only at
// phase 3, where the newest staged load is ~2.5 phases old (distance, not N,
// is what amortizes the wait - m218/m233). Phase-split creates wave role
// diversity so setprio pays (T3->T5) and load/MFMA pipes overlap (m196/m201).
__device__ __forceinline__ void k8_stage_half(const unsigned short* G, unsigned short* ldsb,
                                              int kt, int half, int t){
  #pragma unroll
  for (int it=0; it<2; ++it){
    int ch = it*512 + t;                  // 0..1023 chunks of 16B in this half
    int row = half*128 + (ch>>3), sl = ch&7;
    int koff = (sl ^ (row&7))*8;          // inverse-swizzled global source
    gload16(G + (size_t)row*S_DIM + kt*64 + koff, ldsb + half*8192 + ch*8);
  }
}

__global__ __launch_bounds__(512, 2) void k8_outer(
    const unsigned short* __restrict__ a2, const unsigned short* __restrict__ b2,
    const unsigned short* __restrict__ woutb, const float* __restrict__ num,
    const float* __restrict__ zin, const float* __restrict__ bout,
    float* __restrict__ zout)
{
  __shared__ unsigned short lds[65536];   // 128KB
  int t = threadIdx.x, lane = t&63, w = t>>6;
  int ln15 = lane&15, quad = lane>>4;
  int wm = w>>2, wn = w&3;
  int wr = wm*128, wcol = wn*64;
  int nb = blockIdx.x, mb = blockIdx.y;
  const unsigned short* Ag = a2 + (size_t)(mb*256)*S_DIM;
  const unsigned short* Bg = b2 + (size_t)(nb*256)*S_DIM;

  floatx4 acc[8][4];
  #pragma unroll
  for (int rf=0; rf<8; ++rf)
    #pragma unroll
    for (int cf=0; cf<4; ++cf) acc[rf][cf] = (floatx4){0.f,0.f,0.f,0.f};

  // prologue: stage full tile 0
  k8_stage_half(Ag, lds,         0, 0, t);
  k8_stage_half(Bg, lds + 32768, 0, 0, t);
  k8_stage_half(Ag, lds,         0, 1, t);
  k8_stage_half(Bg, lds + 32768, 0, 1, t);
  vmwait0();
  barrier_nodrain();

  short8 af[4][2], bfv[4][2];
  int sw0 = ((quad    ) ^ (ln15 & 7)) << 3;   // kk0 swizzled slot (ushorts)
  int sw1 = ((quad + 4) ^ (ln15 & 7)) << 3;   // kk1

  for (int kt=0; kt<16; ++kt){
    int sel = kt&1;
    const unsigned short* Ab = lds + sel*16384;
    const unsigned short* Bb = lds + 32768 + sel*16384;
    unsigned short* An = lds + (sel^1)*16384;
    unsigned short* Bn = lds + 32768 + (sel^1)*16384;

    // ---- phase 0: read af(rf0-3)+bf(cf0-1); stage A0',B0'; MFMA q00 ----
    #pragma unroll
    for (int rf=0; rf<4; ++rf){
      af[rf][0] = *(const short8*)(Ab + ((wr + rf*16 + ln15)<<6) + sw0);
      af[rf][1] = *(const short8*)(Ab + ((wr + rf*16 + ln15)<<6) + sw1);
    }
    #pragma unroll
    for (int cf=0; cf<2; ++cf){
      bfv[cf][0] = *(const short8*)(Bb + ((wcol + cf*16 + ln15)<<6) + sw0);
      bfv[cf][1] = *(const short8*)(Bb + ((wcol + cf*16 + ln15)<<6) + sw1);
    }
    if (kt < 15){
      k8_stage_half(Ag, An, kt+1, 0, t);
      k8_stage_half(Bg, Bn, kt+1, 0, t);
    }
    lgkmwait8();
    barrier_nodrain();
    lgkmwait0();
    __builtin_amdgcn_s_setprio(1);
    #pragma unroll
    for (int kk=0; kk<2; ++kk)
      #pragma unroll
      for (int rf=0; rf<4; ++rf)
        #pragma unroll
        for (int cf=0; cf<2; ++cf)
          acc[rf][cf] = __builtin_amdgcn_mfma_f32_16x16x32_bf16(af[rf][kk], bfv[cf][kk], acc[rf][cf], 0, 0, 0);
    __builtin_amdgcn_s_setprio(0);
    barrier_nodrain();

    // ---- phase 1: read bf(cf2-3); stage A1',B1'; MFMA q01 ----
    #pragma unroll
    for (int cf=2; cf<4; ++cf){
      bfv[cf][0] = *(const short8*)(Bb + ((wcol + cf*16 + ln15)<<6) + sw0);
      bfv[cf][1] = *(const short8*)(Bb + ((wcol + cf*16 + ln15)<<6) + sw1);
    }
    if (kt < 15){
      k8_stage_half(Ag, An, kt+1, 1, t);
      k8_stage_half(Bg, Bn, kt+1, 1, t);
    }
    barrier_nodrain();
    lgkmwait0();
    __builtin_amdgcn_s_setprio(1);
    #pragma unroll
    for (int kk=0; kk<2; ++kk)
      #pragma unroll
      for (int rf=0; rf<4; ++rf)
        #pragma unroll
        for (int cf=2; cf<4; ++cf)
          acc[rf][cf] = __builtin_amdgcn_mfma_f32_16x16x32_bf16(af[rf][kk], bfv[cf][kk], acc[rf][cf], 0, 0, 0);
    __builtin_amdgcn_s_setprio(0);
    barrier_nodrain();

    // ---- phase 2: read af(rf4-7, reuse regs); MFMA q10 ----
    #pragma unroll
    for (int rf=0; rf<4; ++rf){
      af[rf][0] = *(const short8*)(Ab + ((wr + 64 + rf*16 + ln15)<<6) + sw0);
      af[rf][1] = *(const short8*)(Ab + ((wr + 64 + rf*16 + ln15)<<6) + sw1);
    }
    barrier_nodrain();
    lgkmwait0();
    __builtin_amdgcn_s_setprio(1);
    #pragma unroll
    for (int kk=0; kk<2; ++kk)
      #pragma unroll
      for (int rf=0; rf<4; ++rf)
        #pragma unroll
        for (int cf=0; cf<2; ++cf)
          acc[4+rf][cf] = __builtin_amdgcn_mfma_f32_16x16x32_bf16(af[rf][kk], bfv[cf][kk], acc[4+rf][cf], 0, 0, 0);
    __builtin_amdgcn_s_setprio(0);
    barrier_nodrain();

    // ---- phase 3: register-only MFMA q11; vmcnt(0) (newest load ~2.5 phases old) ----
    __builtin_amdgcn_s_setprio(1);
    #pragma unroll
    for (int kk=0; kk<2; ++kk)
      #pragma unroll
      for (int rf=0; rf<4; ++rf)
        #pragma unroll
        for (int cf=2; cf<4; ++cf)
          acc[4+rf][cf] = __builtin_amdgcn_mfma_f32_16x16x32_bf16(af[rf][kk], bfv[cf][kk], acc[4+rf][cf], 0, 0, 0);
    __builtin_amdgcn_s_setprio(0);
    vmwait0();
    barrier_nodrain();
  }

  // ---- fused epilogue: z[i,j,:] += P(i,j,:,:) @ wout^T / num + bout ----
  // P = 256x256 bf16 C-tile, staged into LDS as two 128x256 halves (ih).
  unsigned short* P = lds;                      // [128][256]
  #pragma unroll
  for (int ih=0; ih<2; ++ih){
    if (wm == ih){
      #pragma unroll
      for (int rf=0; rf<8; ++rf)
        #pragma unroll
        for (int cf=0; cf<4; ++cf)
          #pragma unroll
          for (int r=0; r<4; ++r)
            P[(rf*16 + quad*4 + r)*256 + wcol + cf*16 + ln15] = f2bf(acc[rf][cf][r]);
    }
    barrier_nodrain();
    // pairs this pass: p = i_ll*8 + j_ll, i_ll in [0,4) (global i = mb*8+ih*4+i_ll), j_ll in [0,8)
    int prow0 = (ln15>>3)*32;                   // i_ll 0..1 (rf2=0)
    int prow1 = prow0 + 64;                     // i_ll 2..3 (rf2=1)
    int pcol  = (ln15&7)*32 + quad*8;
    const unsigned short* wrow = woutb + (size_t)(w*16 + ln15)*1024 + quad*8;
    floatx4 e0 = (floatx4){0.f,0.f,0.f,0.f};
    floatx4 e1 = (floatx4){0.f,0.f,0.f,0.f};
    #pragma unroll 8
    for (int ks=0; ks<32; ++ks){
      short8 wf  = *(const short8*)(wrow + ks*32);
      short8 pa0 = *(const short8*)(P + (prow0 + ks)*256 + pcol);
      short8 pa1 = *(const short8*)(P + (prow1 + ks)*256 + pcol);
      e0 = __builtin_amdgcn_mfma_f32_16x16x32_bf16(pa0, wf, e0, 0, 0, 0);
      e1 = __builtin_amdgcn_mfma_f32_16x16x32_bf16(pa1, wf, e1, 0, 0, 0);
    }
    #pragma unroll
    for (int rf2=0; rf2<2; ++rf2){
      #pragma unroll
      for (int r=0; r<4; ++r){
        int p = rf2*16 + quad*4 + r;
        int i = mb*8 + ih*4 + (p>>3), j = nb*8 + (p&7);
        float nv = num[(size_t)i*N_DIM + j];
        size_t zi = ((size_t)i*N_DIM + j)*CZ + w*16 + ln15;
        float av = (rf2==0) ? e0[r] : e1[r];
        zout[zi] = zin[zi] + av*(1.0f/nv) + bout[w*16 + ln15];
      }
    }
    barrier_nodrain();                          // P reads done before next pass overwrites
  }
}

extern "C" void kernel_launch(void* const* d_in, const int* in_sizes, int n_in,
                              void* d_out, int out_size, void* d_ws, size_t ws_size,
                              hipStream_t stream)
{
  const float* z    = (const float*)d_in[0];
  const float* m    = (const float*)d_in[1];
  const float* tm   = (const float*)d_in[2];
  const float* mask = (const float*)d_in[3];
  const float* lnzg = (const float*)d_in[4];
  const float* lnzb = (const float*)d_in[5];
  const float* wz   = (const float*)d_in[6];
  const float* lnmg = (const float*)d_in[7];
  const float* lnmb = (const float*)d_in[8];
  const float* wm   = (const float*)d_in[9];
  const float* wg   = (const float*)d_in[10];
  const float* wo   = (const float*)d_in[11];
  const float* lntg = (const float*)d_in[12];
  const float* lntb = (const float*)d_in[13];
  const float* fc1  = (const float*)d_in[14];
  const float* fc2  = (const float*)d_in[15];
  const float* fc3  = (const float*)d_in[16];
  const float* lnog = (const float*)d_in[17];
  const float* lnob = (const float*)d_in[18];
  const float* wa   = (const float*)d_in[19];
  const float* wb   = (const float*)d_in[20];
  const float* wout = (const float*)d_in[21];
  const float* bout = (const float*)d_in[22];

  float* zout = (float*)d_out;
  float* mout = zout + (size_t)N_DIM*N_DIM*CZ;

  // z-region of d_out doubles as scratch for buffers dead before k8 writes z:
  char* zs = (char*)d_out;
  unsigned short* mn     = (unsigned short*)zs;               // 50,331,648 B
  float*          logits = (float*)(zs + 50331648);           //  4,718,592 B
  unsigned short* watt   = (unsigned short*)(zs + 55050240);  //  2,359,296 B
  unsigned short* W      = (unsigned short*)(zs + 57409536);  // bf16 weights (dead before k8)
  unsigned short* wgb  = W;          // 16384
  unsigned short* wob  = W + 16384;  // 16384
  unsigned short* fc1b = W + 32768;  // 16384
  unsigned short* fc2b = W + 49152;  // 16384
  unsigned short* fc3b = W + 65536;  // 16384
  unsigned short* wabb = W + 81920;  //  4096

  char* ws = (char*)d_ws;
  unsigned short* v2    = (unsigned short*)ws;                // 201,326,592 B
  unsigned short* o2    = (unsigned short*)(ws + 201326592);  // 201,326,592 B
  float*          num   = (float*)(ws + 402653184);           //     589,824 B
  unsigned short* woutb = (unsigned short*)(ws + 403243008);  //     262,144 B
  unsigned short* a2 = v2;                                    // alias: v2 dead after k4
  unsigned short* b2 = v2 + (size_t)MO*S_DIM;

  kcvt<<<64, 256, 0, stream>>>(wg,  wgb,  16384);
  kcvt<<<64, 256, 0, stream>>>(wo,  wob,  16384);
  kcvt<<<64, 256, 0, stream>>>(fc1, fc1b, 16384);
  kcvt<<<64, 256, 0, stream>>>(fc2, fc2b, 16384);
  kcvt<<<64, 256, 0, stream>>>(fc3, fc3b, 16384);
  kcvt<<<8,  256, 0, stream>>>(wa,  wabb, 2048);
  kcvt<<<8,  256, 0, stream>>>(wb,  wabb+2048, 2048);
  kcvt<<<512,256, 0, stream>>>(wout, woutb, 131072);

  k1_logits  <<<36864, 256, 0, stream>>>(z, tm, lnzg, lnzb, wz, logits);
  k2_softmax <<<768, 256, 0, stream>>>(logits, watt);
  k3_lnm_v   <<<dim3(24,1024), 256, 0, stream>>>(m, lnmg, lnmb, wm, mn, v2);
  k7_num     <<<dim3(24,24), 256, 0, stream>>>(mask, num);
  k4_attn    <<<dim3(256,3,8), 256, 0, stream>>>(watt, v2, o2);
  k5m        <<<dim3(8,384), 256, 0, stream>>>(m, mn, o2, wgb, wob, mout);
  k6m        <<<dim3(8,384), 256, 0, stream>>>(mout, mask, lntg, lntb, fc1b, fc2b, fc3b,
                                               lnog, lnob, wabb, a2, b2);
  k8_outer   <<<dim3(48,48), 512, 0, stream>>>(a2, b2, woutb, num, z, bout, zout);
}